// Round 15
// baseline (721.433 us; speedup 1.0000x reference)
//
#include <hip/hip_runtime.h>
#include <cstdint>
#include <cmath>

#define NB 4
#define NS 2048
#define ND 2048
#define NH 16
#define NDH 128
#define NM (NB*NS)   // 8192

typedef unsigned short u16;
typedef __bf16 bf16x8 __attribute__((ext_vector_type(8)));
typedef u16    u16x8  __attribute__((ext_vector_type(8)));
typedef u16    u16x4  __attribute__((ext_vector_type(4)));
typedef float  f32x4  __attribute__((ext_vector_type(4)));
typedef float  f32x16 __attribute__((ext_vector_type(16)));
typedef unsigned u32x4_t __attribute__((ext_vector_type(4)));

__device__ __forceinline__ u16 f2bf(float f) {
  unsigned u = __float_as_uint(f);
  u += 0x7fffu + ((u >> 16) & 1u);   // RNE
  return (u16)(u >> 16);
}
__device__ __forceinline__ float bf2f(u16 h) {
  return __uint_as_float(((unsigned)h) << 16);
}
__device__ __forceinline__ void gld16(const void* g, void* l) {
  __builtin_amdgcn_global_load_lds((__attribute__((address_space(1))) void*)g,
                                   (__attribute__((address_space(3))) void*)l,
                                   16, 0, 0);
}
__device__ __forceinline__ f32x4 mfma_bf16(bf16x8 a, bf16x8 b, f32x4 c) {
  return __builtin_amdgcn_mfma_f32_16x16x32_bf16(a, b, c, 0, 0, 0);
}
__device__ __forceinline__ f32x16 mfma32_bf16(bf16x8 a, bf16x8 b, f32x16 c) {
  return __builtin_amdgcn_mfma_f32_32x32x16_bf16(a, b, c, 0, 0, 0);
}
__device__ __forceinline__ unsigned cvtpk(float lo, float hi) {
  unsigned r;
  asm("v_cvt_pk_bf16_f32 %0, %1, %2" : "=v"(r) : "v"(lo), "v"(hi));
  return r;
}
__device__ __forceinline__ void p32swap(unsigned &a, unsigned &b) {
  asm volatile("v_permlane32_swap_b32 %0, %1" : "+v"(a), "+v"(b));
}

// P -> bf16 A-frag (T12): 4 cvt_pk + 2 permlane32_swap per 8 values
#define MKPA(P, B, OUT) {                              \
      unsigned a0 = cvtpk(P[(B)+0], P[(B)+1]);         \
      unsigned b0 = cvtpk(P[(B)+4], P[(B)+5]);         \
      p32swap(a0, b0);                                 \
      unsigned a1 = cvtpk(P[(B)+2], P[(B)+3]);         \
      unsigned b1 = cvtpk(P[(B)+6], P[(B)+7]);         \
      p32swap(a1, b1);                                 \
      u32x4_t w_; w_[0]=a0; w_[1]=a1; w_[2]=b0; w_[3]=b1; \
      OUT = *(bf16x8*)&w_; }

// ---------------- fp32 -> bf16 convert (8 elems/thread) ----------------
__global__ void cvt_bf16_kernel(const float* __restrict__ in, u16* __restrict__ out, int n8) {
  int i = blockIdx.x * 256 + threadIdx.x;
  if (i >= n8) return;
  const float4* p = (const float4*)in + (size_t)i * 2;
  float4 a = p[0], b = p[1];
  u16x8 r;
  r[0]=f2bf(a.x); r[1]=f2bf(a.y); r[2]=f2bf(a.z); r[3]=f2bf(a.w);
  r[4]=f2bf(b.x); r[5]=f2bf(b.y); r[6]=f2bf(b.z); r[7]=f2bf(b.w);
  ((u16x8*)out)[i] = r;
}

// 4 weight matrices in one dispatch
__global__ void cvt4_bf16_kernel(const float* __restrict__ i0, const float* __restrict__ i1,
                                 const float* __restrict__ i2, const float* __restrict__ i3,
                                 u16* o0, u16* o1, u16* o2, u16* o3, int n8each) {
  int idx = blockIdx.x * 256 + threadIdx.x;
  int w = idx / n8each, i = idx - w * n8each;
  if (w >= 4) return;
  const float* in = (w == 0) ? i0 : (w == 1) ? i1 : (w == 2) ? i2 : i3;
  u16* out = (w == 0) ? o0 : (w == 1) ? o1 : (w == 2) ? o2 : o3;
  const float4* p = (const float4*)in + (size_t)i * 2;
  float4 a = p[0], b = p[1];
  u16x8 r;
  r[0]=f2bf(a.x); r[1]=f2bf(a.y); r[2]=f2bf(a.z); r[3]=f2bf(a.w);
  r[4]=f2bf(b.x); r[5]=f2bf(b.y); r[6]=f2bf(b.z); r[7]=f2bf(b.w);
  ((u16x8*)out)[i] = r;
}

// ---------------- RoPE tables: cos/sin [S][64] ----------------
__global__ void rope_tables_kernel(float* __restrict__ cosT, float* __restrict__ sinT) {
  int s = blockIdx.x, d = threadIdx.x;
  double inv = pow(10000.0, -(double)d / 64.0);
  float ang = (float)((double)s * inv);
  cosT[s*64 + d] = cosf(ang);
  sinT[s*64 + d] = sinf(ang);
}

// ---------------- RoPE apply, Q and K in one dispatch ----------------
__global__ void rope_apply_kernel(u16* __restrict__ Qb, u16* __restrict__ Kb,
                                  const float* __restrict__ cosT,
                                  const float* __restrict__ sinT, int nthr) {
  int gidx = blockIdx.x * 256 + threadIdx.x;
  u16* X = (gidx < nthr) ? Qb : Kb;
  int idx = (gidx < nthr) ? gidx : gidx - nthr;
  int pc = idx & 7, h = (idx >> 3) & (NH - 1), m = idx >> 7;
  int s = m & (NS - 1);
  int d0 = pc * 8;
  size_t base = (size_t)m * ND + h * NDH + d0;
  u16x8 v0 = *(const u16x8*)(X + base);
  u16x8 v1 = *(const u16x8*)(X + base + 64);
  u16x8 r0, r1;
#pragma unroll
  for (int j = 0; j < 8; ++j) {
    float c  = cosT[s*64 + d0 + j];
    float sn = sinT[s*64 + d0 + j];
    float x0 = bf2f(v0[j]), x1 = bf2f(v1[j]);
    r0[j] = f2bf(x0 * c - x1 * sn);
    r1[j] = f2bf(x1 * c + x0 * sn);
  }
  *(u16x8*)(X + base)      = r0;
  *(u16x8*)(X + base + 64) = r1;
}

// ---------------- bf16 GEMM, 256x256 tile, 8-phase, 16x16x32 MFMA ----------
// R13 schedule (best of R8/R12/R13/R14): barriers at even phases only,
// vmcnt(4) at phases 4/8; conflict-free swizzle keyed on row bits 1..2.
#define BARX do { __builtin_amdgcn_s_barrier(); __builtin_amdgcn_sched_barrier(0); } while (0)
#define VM4  do { asm volatile("s_waitcnt vmcnt(4)" ::: "memory"); \
                  __builtin_amdgcn_sched_barrier(0); } while (0)
#define GP(BUF, KS, MH, LOADB, WAITV, DOBAR, STAGE) do {                          \
  bf16x8 af[4];                                                                   \
  _Pragma("unroll")                                                               \
  for (int mf = 0; mf < 4; ++mf)                                                  \
    af[mf] = *(const bf16x8*)(Asb + (BUF)*32768 + (KS)*16384 + arow + ((MH)*4+mf)*1024); \
  if (LOADB) {                                                                    \
    _Pragma("unroll")                                                             \
    for (int nf = 0; nf < 4; ++nf)                                                \
      bfr[nf] = *(const bf16x8*)(Bsb + (BUF)*32768 + (KS)*16384 + brow + nf*1024); \
  }                                                                               \
  STAGE;                                                                          \
  __builtin_amdgcn_s_setprio(1);                                                  \
  _Pragma("unroll")                                                               \
  for (int mf = 0; mf < 4; ++mf)                                                  \
    _Pragma("unroll")                                                             \
    for (int nf = 0; nf < 4; ++nf)                                                \
      acc[(MH)*4+mf][nf] = mfma_bf16(af[mf], bfr[nf], acc[(MH)*4+mf][nf]);        \
  __builtin_amdgcn_s_setprio(0);                                                  \
  if (WAITV) VM4;                                                                 \
  if (DOBAR) BARX;                                                                \
} while (0)

template <typename OutT>
__global__ __launch_bounds__(512, 2) void gemm256_kernel(
    const u16* __restrict__ A,
    const u16* __restrict__ B0, const u16* __restrict__ B1, const u16* __restrict__ B2,
    OutT* __restrict__ C0, OutT* __restrict__ C1, OutT* __restrict__ C2,
    int Nd, int Kd) {
  __shared__ __align__(16) char Asb[65536];
  __shared__ __align__(16) char Bsb[65536];
  int tid = threadIdx.x;
  int wave = tid >> 6, lane = tid & 63;
  int li = lane & 15, lg = lane >> 4;
  int wr = wave >> 2, wc = wave & 3;           // 2 x 4 wave grid
  int w  = (int)blockIdx.x >> 8;               // matrix select (fused QKV)
  int tb = (int)blockIdx.x & 255;
  const u16* Bw = (w == 0) ? B0 : (w == 1) ? B1 : B2;
  OutT*      C  = (w == 0) ? C0 : (w == 1) ? C1 : C2;
  int NTn = Nd >> 8;
  int swz = (tb & 7) * 32 + (tb >> 3);         // XCD swizzle over 256 tiles
  int m0 = (swz / NTn) << 8, n0 = (swz % NTn) << 8;

  int rswz = (lg * 16) ^ (((li >> 1) & 3) << 4);
  int arow = (wr * 128 + li) * 64 + rswz;
  int brow = (wc *  64 + li) * 64 + rswz;

  int srow = wave * 16 + (lane >> 2);
  int scswz = ((lane & 3) * 16) ^ (((srow >> 1) & 3) << 4);
  size_t rowB = (size_t)Kd * 2;
  const char* Asrc = (const char*)A  + (size_t)(m0 + srow) * rowB + scswz;
  const char* Bsrc = (const char*)Bw + (size_t)(n0 + srow) * rowB + scswz;
  char* Adst = Asb + wave * 1024;
  char* Bdst = Bsb + wave * 1024;
  size_t half2 = rowB << 7;

  auto stageA = [&](int buf, int ks, int tile) {
    const char* s = Asrc + (size_t)tile * 128 + ks * 64;
    char* d = Adst + buf * 32768 + ks * 16384;
    gld16(s, d);
    gld16(s + half2, d + 8192);
  };
  auto stageB = [&](int buf, int ks, int tile) {
    const char* s = Bsrc + (size_t)tile * 128 + ks * 64;
    char* d = Bdst + buf * 32768 + ks * 16384;
    gld16(s, d);
    gld16(s + half2, d + 8192);
  };

  f32x4 acc[8][4] = {};
  bf16x8 bfr[4];

  int NKT = Kd >> 6;
  int NIT = NKT >> 1;

  stageA(0, 0, 0); stageA(0, 1, 0); stageB(0, 0, 0); stageB(0, 1, 0);
  stageA(1, 0, 1); stageB(1, 0, 1);
  asm volatile("s_waitcnt vmcnt(4)" ::: "memory");
  __builtin_amdgcn_sched_barrier(0);
  BARX;

  for (int j = 0; j < NIT; ++j) {
    int t1  = 2*j + 1;
    int tn0 = (2*j + 2) & (NKT - 1);
    int tn1 = (2*j + 3) & (NKT - 1);
    GP(0, 0, 0, true,  false, false, { stageA(1, 1, t1);  });
    GP(0, 0, 1, false, false, true,  { stageB(1, 1, t1);  });
    GP(0, 1, 1, true,  false, false, { stageA(0, 0, tn0); });
    GP(0, 1, 0, false, true,  true,  { stageB(0, 0, tn0); });
    GP(1, 0, 0, true,  false, false, { stageA(0, 1, tn0); });
    GP(1, 0, 1, false, false, true,  { stageB(0, 1, tn0); });
    GP(1, 1, 1, true,  false, false, { stageA(1, 0, tn1); });
    GP(1, 1, 0, false, true,  true,  { stageB(1, 0, tn1); });
  }
  asm volatile("s_waitcnt vmcnt(0)" ::: "memory");

  int rbase = m0 + wr*128 + lg*4;
  int cbase = n0 + wc*64 + li;
#pragma unroll
  for (int am = 0; am < 8; ++am)
#pragma unroll
    for (int nf = 0; nf < 4; ++nf)
#pragma unroll
      for (int r = 0; r < 4; ++r) {
        size_t off = (size_t)(rbase + am*16 + r) * Nd + (cbase + nf*16);
        if constexpr (sizeof(OutT) == 2) C[off] = f2bf(acc[am][nf][r]);
        else                             C[off] = acc[am][nf][r];
      }
}

// ---------------- causal flash attention, paired q-tiles ----------------
// R15: each block owns q-tile PAIR (qtA = 4+y, qtB = 3-y), y = blockIdx.y in
// 0..3 -> every block does exactly (4qtA+4)+(4qtB+4) = 36 compute steps
// (equal work, no dispatch tail), and each staged kv-tile feeds BOTH states
// while kv < q0B+256 (KV HBM traffic halved, 2x MFMA per staged tile).
// Grid 256 blocks = 1/CU.  Dual state: oA/oB (f32x16 x4 each), mA/lA/mB/lB,
// qfA/qfB.  Both states' Ks reads stay before BAR-B (same hazard proof as
// single-state).  doB is wave-uniform -> uniform barrier counts.
#define QKSM(SUF) do {                                                         \
    f32x16 p0 = {}, p1 = {};                                                   \
    __builtin_amdgcn_s_setprio(1);                                             \
    _Pragma("unroll")                                                          \
    for (int ds = 0; ds < 8; ++ds) {                                           \
      bf16x8 kf0 = *(const bf16x8*)(ksb + ((ql*256 + ds*32 + hi*16) ^ swzl));  \
      p0 = mfma32_bf16(kf0, qf##SUF[ds], p0);                                  \
      bf16x8 kf1 = *(const bf16x8*)(ksb + (((32+ql)*256 + ds*32 + hi*16) ^ swzl)); \
      p1 = mfma32_bf16(kf1, qf##SUF[ds], p1);                                  \
    }                                                                          \
    __builtin_amdgcn_s_setprio(0);                                             \
    if (kv0 + 63 > qw##SUF) {                                                  \
      int thresh = qa##SUF - kv0 - 4*hi;                                       \
      _Pragma("unroll")                                                        \
      for (int r = 0; r < 16; ++r) {                                           \
        int c0 = (r & 3) + 8*(r >> 2);                                         \
        p0[r] = (c0      > thresh) ? -INFINITY : p0[r];                        \
        p1[r] = (c0 + 32 > thresh) ? -INFINITY : p1[r];                        \
      }                                                                        \
    }                                                                          \
    float mx[16];                                                              \
    _Pragma("unroll")                                                          \
    for (int r = 0; r < 16; ++r) mx[r] = fmaxf(p0[r], p1[r]);                  \
    _Pragma("unroll")                                                          \
    for (int s_ = 8; s_ > 0; s_ >>= 1)                                         \
      _Pragma("unroll")                                                        \
      for (int r = 0; r < 8; ++r) if (r < s_) mx[r] = fmaxf(mx[r], mx[r + s_]); \
    float pmax = fmaxf(mx[0], __shfl_xor(mx[0], 32, 64));                      \
    if (!__all(pmax <= m##SUF + 8.f)) {                                        \
      float mn = fmaxf(m##SUF, pmax);                                          \
      float corr = __builtin_amdgcn_exp2f(m##SUF - mn);                        \
      m##SUF = mn; l##SUF *= corr;                                             \
      _Pragma("unroll")                                                        \
      for (int r = 0; r < 16; ++r) {                                           \
        float cw = __shfl(corr, (r & 3) + 8*(r >> 2) + 4*hi, 64);              \
        o##SUF##0[r] *= cw; o##SUF##1[r] *= cw;                                \
        o##SUF##2[r] *= cw; o##SUF##3[r] *= cw;                                \
      }                                                                        \
    }                                                                          \
    float sm[16];                                                              \
    _Pragma("unroll")                                                          \
    for (int r = 0; r < 16; ++r) {                                             \
      p0[r] = __builtin_amdgcn_exp2f(p0[r] - m##SUF);                          \
      p1[r] = __builtin_amdgcn_exp2f(p1[r] - m##SUF);                          \
      sm[r] = p0[r] + p1[r];                                                   \
    }                                                                          \
    _Pragma("unroll")                                                          \
    for (int s_ = 8; s_ > 0; s_ >>= 1)                                         \
      _Pragma("unroll")                                                        \
      for (int r = 0; r < 8; ++r) if (r < s_) sm[r] += sm[r + s_];             \
    l##SUF += sm[0] + __shfl_xor(sm[0], 32, 64);                               \
    MKPA(p0, 0, pa##SUF##0)                                                    \
    MKPA(p0, 8, pa##SUF##1)                                                    \
    MKPA(p1, 0, pa##SUF##2)                                                    \
    MKPA(p1, 8, pa##SUF##3)                                                    \
  } while (0)

#define PVT1(OT, T, P0, P1, P2, P3)                                            \
    _Pragma("unroll")                                                          \
    for (int ks_ = 0; ks_ < 4; ++ks_) {                                        \
      int a_ = ((((T)*32 + ql)*128 + ks_*32 + hi*16) ^ vswz);                  \
      bf16x8 vf = *(const bf16x8*)(vtb + a_);                                  \
      OT = mfma32_bf16(ks_==0?P0:ks_==1?P1:ks_==2?P2:P3, vf, OT);              \
    }
#define PVS(SUF) do {                                                          \
    __builtin_amdgcn_s_setprio(1);                                             \
    PVT1(o##SUF##0, 0, pa##SUF##0, pa##SUF##1, pa##SUF##2, pa##SUF##3)         \
    PVT1(o##SUF##1, 1, pa##SUF##0, pa##SUF##1, pa##SUF##2, pa##SUF##3)         \
    PVT1(o##SUF##2, 2, pa##SUF##0, pa##SUF##1, pa##SUF##2, pa##SUF##3)         \
    PVT1(o##SUF##3, 3, pa##SUF##0, pa##SUF##1, pa##SUF##2, pa##SUF##3)         \
    __builtin_amdgcn_s_setprio(0);                                             \
  } while (0)

__global__ __launch_bounds__(512, 2) void flash_attn_kernel(
    const u16* __restrict__ Q, const u16* __restrict__ K, const u16* __restrict__ V,
    u16* __restrict__ O) {
  __shared__ __align__(16) u16 Ks[2*64*128];  // 32 KB swizzled [kv][dh]
  __shared__ __align__(16) u16 Vt[2*128*64];  // 32 KB swizzled [dh][kv]
  int tid = threadIdx.x, wv = tid >> 6, lane = tid & 63;
  int ql = lane & 31, hi = lane >> 5;
  int b = blockIdx.x >> 4, h = blockIdx.x & 15;
  int y = blockIdx.y;
  int qtA = 4 + y, qtB = 3 - y;
  int q0A = qtA << 8, q0B = qtB << 8;
  int qwA = q0A + wv*32, qwB = q0B + wv*32;
  int qaA = qwA + ql,  qaB = qwB + ql;
  int swzl = (ql & 7) << 4;         // Ks swizzle (256-B rows)
  int vswz = ((ql >> 1) & 7) << 4;  // Vt read swizzle
  const float qscale = 0.08838834764831845f * 1.4426950408889634f;

  bf16x8 qfA[8], qfB[8];
  {
    const u16* qpA = Q + (size_t)(b*NS + qaA) * ND + h*NDH + hi*8;
    const u16* qpB = Q + (size_t)(b*NS + qaB) * ND + h*NDH + hi*8;
#pragma unroll
    for (int ds = 0; ds < 8; ++ds) {
      u16x8 tA = *(const u16x8*)(qpA + ds*16);
      u16x8 tB = *(const u16x8*)(qpB + ds*16);
      u16x8 rA, rB;
#pragma unroll
      for (int j = 0; j < 8; ++j) {
        rA[j] = f2bf(bf2f(tA[j]) * qscale);
        rB[j] = f2bf(bf2f(tB[j]) * qscale);
      }
      qfA[ds] = *(bf16x8*)&rA;
      qfB[ds] = *(bf16x8*)&rB;
    }
  }
  f32x16 oA0 = {}, oA1 = {}, oA2 = {}, oA3 = {};
  f32x16 oB0 = {}, oB1 = {}, oB2 = {}, oB3 = {};
  float mA = -INFINITY, lA = 0.f, mB = -INFINITY, lB = 0.f;
  bf16x8 paA0, paA1, paA2, paA3, paB0, paB1, paB2, paB3;

  const char* Kg = (const char*)(K + (size_t)b*NS*ND + h*NDH);
  const char* Vg = (const char*)(V + (size_t)b*NS*ND + h*NDH);
  const int ROWB = ND * 2;

  int p   = tid & 31;    // dh pair for V repack
  int kvg = tid >> 5;    // kv chunk 0..15 (4 kv rows each)

  auto issueKV = [&](int kv0, int buf, unsigned (&dlo)[4], unsigned (&dhi)[4]) {
    const char* vrow = Vg + (size_t)(kv0 + kvg*4) * ROWB;
#pragma unroll
    for (int j = 0; j < 4; ++j) {
      dlo[j] = *(const unsigned*)(vrow + j*ROWB + p*4);
      dhi[j] = *(const unsigned*)(vrow + j*ROWB + 128 + p*4);
    }
    char* ksb = (char*)Ks + buf*16384;
#pragma unroll
    for (int c = 0; c < 2; ++c) {
      int s = c*8192 + wv*1024 + lane*16;
      int row = s >> 8;
      int within = (s & 255) ^ ((row & 7) << 4);
      gld16(Kg + (size_t)(kv0 + row)*ROWB + within, ksb + c*8192 + wv*1024);
    }
    __builtin_amdgcn_sched_barrier(0);
  };

  auto dostep = [&](int kv0, int buf, const unsigned (&dlo)[4], const unsigned (&dhi)[4],
                    bool hasNext) {
    if (hasNext) asm volatile("s_waitcnt vmcnt(10)" ::: "memory");
    else         asm volatile("s_waitcnt vmcnt(0)"  ::: "memory");
    __builtin_amdgcn_sched_barrier(0);
    __builtin_amdgcn_s_barrier();        // BAR-A: K(t) landed
    __builtin_amdgcn_sched_barrier(0);

    char* vtb = (char*)Vt + buf*16384;
    const char* ksb = (const char*)Ks + buf*16384;

    // Vt write: rows {2p,2p+1,2p+64,2p+65} all swizzle to granule p&7
    {
      u16x4 rA, rB, rC, rD;
#pragma unroll
      for (int j = 0; j < 4; ++j) {
        rA[j] = (u16)dlo[j]; rB[j] = (u16)(dlo[j] >> 16);
        rC[j] = (u16)dhi[j]; rD[j] = (u16)(dhi[j] >> 16);
      }
      int ws = (p & 7) << 4;
      *(u16x4*)(vtb + (((2*p   )*128 + kvg*8) ^ ws)) = rA;
      *(u16x4*)(vtb + (((2*p+ 1)*128 + kvg*8) ^ ws)) = rB;
      *(u16x4*)(vtb + (((2*p+64)*128 + kvg*8) ^ ws)) = rC;
      *(u16x4*)(vtb + (((2*p+65)*128 + kvg*8) ^ ws)) = rD;
    }

    bool doB = kv0 < q0B + 256;          // wave-uniform
    QKSM(A);
    if (doB) QKSM(B);

    asm volatile("s_waitcnt lgkmcnt(0)" ::: "memory");
    __builtin_amdgcn_sched_barrier(0);
    __builtin_amdgcn_s_barrier();        // BAR-B: Vt[buf] visible
    __builtin_amdgcn_sched_barrier(0);

    PVS(A);
    if (doB) PVS(B);
  };

  int nt = 4*qtA + 4;                    // kv tiles 0 .. q0A+255  (>= 20)
  unsigned dloA_[4], dhiA_[4], dloB_[4], dhiB_[4];
  issueKV(0, 0, dloA_, dhiA_);
  for (int t = 0; ; t += 2) {
    bool h1 = (t+1 < nt);
    if (h1) issueKV((t+1)*64, 1, dloB_, dhiB_);
    dostep(t*64, 0, dloA_, dhiA_, h1);
    if (!h1) break;
    bool h2 = (t+2 < nt);
    if (h2) issueKV((t+2)*64, 0, dloA_, dhiA_);
    dostep((t+1)*64, 1, dloB_, dhiB_, h2);
    if (!h2) break;
  }

  // epilogue: both states
  float invA = 1.0f / lA, invB = 1.0f / lB;
#pragma unroll
  for (int r = 0; r < 16; ++r) {
    int crow = (r & 3) + 8*(r >> 2) + 4*hi;
    float ivA = __shfl(invA, crow, 64);
    float ivB = __shfl(invB, crow, 64);
    size_t baseA = (size_t)(b*NS + qwA + crow) * ND + h*NDH + ql;
    size_t baseB = (size_t)(b*NS + qwB + crow) * ND + h*NDH + ql;
    O[baseA +  0] = f2bf(oA0[r] * ivA);
    O[baseA + 32] = f2bf(oA1[r] * ivA);
    O[baseA + 64] = f2bf(oA2[r] * ivA);
    O[baseA + 96] = f2bf(oA3[r] * ivA);
    O[baseB +  0] = f2bf(oB0[r] * ivB);
    O[baseB + 32] = f2bf(oB1[r] * ivB);
    O[baseB + 64] = f2bf(oB2[r] * ivB);
    O[baseB + 96] = f2bf(oB3[r] * ivB);
  }
}

// ---------------- launch ----------------
extern "C" void kernel_launch(void* const* d_in, const int* in_sizes, int n_in,
                              void* d_out, int out_size, void* d_ws, size_t ws_size,
                              hipStream_t stream) {
  const float* x  = (const float*)d_in[0];
  // d_in[1] = attn_mask (causal, handled analytically)
  const float* Wq = (const float*)d_in[2];
  const float* Wk = (const float*)d_in[3];
  const float* Wv = (const float*)d_in[4];
  const float* Wo = (const float*)d_in[5];

  char* ws = (char*)d_ws;
  const size_t SZ_MD = (size_t)NM * ND * 2;
  const size_t SZ_W  = (size_t)ND * ND * 2;
  u16* xb  = (u16*)(ws);
  u16* Qb  = (u16*)(ws + SZ_MD);
  u16* Kb  = (u16*)(ws + 2*SZ_MD);
  u16* Vb  = (u16*)(ws + 3*SZ_MD);
  u16* Ab  = (u16*)(ws + 4*SZ_MD);
  u16* Wqb = (u16*)(ws + 5*SZ_MD);
  u16* Wkb = (u16*)(ws + 5*SZ_MD + SZ_W);
  u16* Wvb = (u16*)(ws + 5*SZ_MD + 2*SZ_W);
  u16* Wob = (u16*)(ws + 5*SZ_MD + 3*SZ_W);
  float* cosT = (float*)(ws + 5*SZ_MD + 4*SZ_W);
  float* sinT = (float*)(ws + 5*SZ_MD + 4*SZ_W + (size_t)NS*64*4);
  size_t needed = 5*SZ_MD + 4*SZ_W + 2*(size_t)NS*64*4;
  if (ws_size < needed) return;

  {
    int n8 = (NM * ND) / 8;
    cvt_bf16_kernel<<<(n8 + 255)/256, 256, 0, stream>>>(x, xb, n8);
    int w8 = (ND * ND) / 8;
    cvt4_bf16_kernel<<<(4*w8 + 255)/256, 256, 0, stream>>>(Wq, Wk, Wv, Wo,
                                                           Wqb, Wkb, Wvb, Wob, w8);
  }
  rope_tables_kernel<<<NS, 64, 0, stream>>>(cosT, sinT);

  // fused QKV projection: one dispatch, 768 blocks
  gemm256_kernel<u16><<<3*256, 512, 0, stream>>>(xb, Wqb, Wkb, Wvb,
                                                 Qb, Kb, Vb, ND, ND);

  {
    int nthr = NM * NH * 8;
    rope_apply_kernel<<<(2*nthr)/256, 256, 0, stream>>>(Qb, Kb, cosT, sinT, nthr);
  }

  // paired q-tiles: grid (B*H, 4), each block = 36 equal compute steps
  flash_attn_kernel<<<dim3(NB*NH, 4), 512, 0, stream>>>(Qb, Kb, Vb, Ab);

  gemm256_kernel<float><<<256, 512, 0, stream>>>(Ab, Wob, nullptr, nullptr,
                                                 (float*)d_out, nullptr, nullptr, ND, ND);
}

// Round 16
// 424.733 us; speedup vs baseline: 1.6986x; 1.6986x over previous
//
#include <hip/hip_runtime.h>
#include <cstdint>
#include <cmath>

#define NB 4
#define NS 2048
#define ND 2048
#define NH 16
#define NDH 128
#define NM (NB*NS)   // 8192

typedef unsigned short u16;
typedef __bf16 bf16x8 __attribute__((ext_vector_type(8)));
typedef u16    u16x8  __attribute__((ext_vector_type(8)));
typedef u16    u16x4  __attribute__((ext_vector_type(4)));
typedef float  f32x4  __attribute__((ext_vector_type(4)));
typedef float  f32x16 __attribute__((ext_vector_type(16)));
typedef unsigned u32x4_t __attribute__((ext_vector_type(4)));

__device__ __forceinline__ u16 f2bf(float f) {
  unsigned u = __float_as_uint(f);
  u += 0x7fffu + ((u >> 16) & 1u);   // RNE
  return (u16)(u >> 16);
}
__device__ __forceinline__ float bf2f(u16 h) {
  return __uint_as_float(((unsigned)h) << 16);
}
__device__ __forceinline__ void gld16(const void* g, void* l) {
  __builtin_amdgcn_global_load_lds((__attribute__((address_space(1))) void*)g,
                                   (__attribute__((address_space(3))) void*)l,
                                   16, 0, 0);
}
__device__ __forceinline__ f32x4 mfma_bf16(bf16x8 a, bf16x8 b, f32x4 c) {
  return __builtin_amdgcn_mfma_f32_16x16x32_bf16(a, b, c, 0, 0, 0);
}
__device__ __forceinline__ f32x16 mfma32_bf16(bf16x8 a, bf16x8 b, f32x16 c) {
  return __builtin_amdgcn_mfma_f32_32x32x16_bf16(a, b, c, 0, 0, 0);
}
__device__ __forceinline__ unsigned cvtpk(float lo, float hi) {
  unsigned r;
  asm("v_cvt_pk_bf16_f32 %0, %1, %2" : "=v"(r) : "v"(lo), "v"(hi));
  return r;
}
__device__ __forceinline__ void p32swap(unsigned &a, unsigned &b) {
  asm volatile("v_permlane32_swap_b32 %0, %1" : "+v"(a), "+v"(b));
}

// ---------------- fp32 -> bf16 convert (8 elems/thread) ----------------
__global__ void cvt_bf16_kernel(const float* __restrict__ in, u16* __restrict__ out, int n8) {
  int i = blockIdx.x * 256 + threadIdx.x;
  if (i >= n8) return;
  const float4* p = (const float4*)in + (size_t)i * 2;
  float4 a = p[0], b = p[1];
  u16x8 r;
  r[0]=f2bf(a.x); r[1]=f2bf(a.y); r[2]=f2bf(a.z); r[3]=f2bf(a.w);
  r[4]=f2bf(b.x); r[5]=f2bf(b.y); r[6]=f2bf(b.z); r[7]=f2bf(b.w);
  ((u16x8*)out)[i] = r;
}

// 4 weight matrices in one dispatch
__global__ void cvt4_bf16_kernel(const float* __restrict__ i0, const float* __restrict__ i1,
                                 const float* __restrict__ i2, const float* __restrict__ i3,
                                 u16* o0, u16* o1, u16* o2, u16* o3, int n8each) {
  int idx = blockIdx.x * 256 + threadIdx.x;
  int w = idx / n8each, i = idx - w * n8each;
  if (w >= 4) return;
  const float* in = (w == 0) ? i0 : (w == 1) ? i1 : (w == 2) ? i2 : i3;
  u16* out = (w == 0) ? o0 : (w == 1) ? o1 : (w == 2) ? o2 : o3;
  const float4* p = (const float4*)in + (size_t)i * 2;
  float4 a = p[0], b = p[1];
  u16x8 r;
  r[0]=f2bf(a.x); r[1]=f2bf(a.y); r[2]=f2bf(a.z); r[3]=f2bf(a.w);
  r[4]=f2bf(b.x); r[5]=f2bf(b.y); r[6]=f2bf(b.z); r[7]=f2bf(b.w);
  ((u16x8*)out)[i] = r;
}

// ---------------- RoPE tables: cos/sin [S][64] ----------------
__global__ void rope_tables_kernel(float* __restrict__ cosT, float* __restrict__ sinT) {
  int s = blockIdx.x, d = threadIdx.x;
  double inv = pow(10000.0, -(double)d / 64.0);
  float ang = (float)((double)s * inv);
  cosT[s*64 + d] = cosf(ang);
  sinT[s*64 + d] = sinf(ang);
}

// ---------------- RoPE apply, Q and K in one dispatch ----------------
__global__ void rope_apply_kernel(u16* __restrict__ Qb, u16* __restrict__ Kb,
                                  const float* __restrict__ cosT,
                                  const float* __restrict__ sinT, int nthr) {
  int gidx = blockIdx.x * 256 + threadIdx.x;
  u16* X = (gidx < nthr) ? Qb : Kb;
  int idx = (gidx < nthr) ? gidx : gidx - nthr;
  int pc = idx & 7, h = (idx >> 3) & (NH - 1), m = idx >> 7;
  int s = m & (NS - 1);
  int d0 = pc * 8;
  size_t base = (size_t)m * ND + h * NDH + d0;
  u16x8 v0 = *(const u16x8*)(X + base);
  u16x8 v1 = *(const u16x8*)(X + base + 64);
  u16x8 r0, r1;
#pragma unroll
  for (int j = 0; j < 8; ++j) {
    float c  = cosT[s*64 + d0 + j];
    float sn = sinT[s*64 + d0 + j];
    float x0 = bf2f(v0[j]), x1 = bf2f(v1[j]);
    r0[j] = f2bf(x0 * c - x1 * sn);
    r1[j] = f2bf(x1 * c + x0 * sn);
  }
  *(u16x8*)(X + base)      = r0;
  *(u16x8*)(X + base + 64) = r1;
}

// ---------------- bf16 GEMM, 256x256 tile, 8-phase, 16x16x32 MFMA ----------
// R13 schedule (best of R8/R12/R13/R14): barriers at even phases only,
// vmcnt(4) at phases 4/8; conflict-free swizzle keyed on row bits 1..2.
#define BARX do { __builtin_amdgcn_s_barrier(); __builtin_amdgcn_sched_barrier(0); } while (0)
#define VM4  do { asm volatile("s_waitcnt vmcnt(4)" ::: "memory"); \
                  __builtin_amdgcn_sched_barrier(0); } while (0)
#define GP(BUF, KS, MH, LOADB, WAITV, DOBAR, STAGE) do {                          \
  bf16x8 af[4];                                                                   \
  _Pragma("unroll")                                                               \
  for (int mf = 0; mf < 4; ++mf)                                                  \
    af[mf] = *(const bf16x8*)(Asb + (BUF)*32768 + (KS)*16384 + arow + ((MH)*4+mf)*1024); \
  if (LOADB) {                                                                    \
    _Pragma("unroll")                                                             \
    for (int nf = 0; nf < 4; ++nf)                                                \
      bfr[nf] = *(const bf16x8*)(Bsb + (BUF)*32768 + (KS)*16384 + brow + nf*1024); \
  }                                                                               \
  STAGE;                                                                          \
  __builtin_amdgcn_s_setprio(1);                                                  \
  _Pragma("unroll")                                                               \
  for (int mf = 0; mf < 4; ++mf)                                                  \
    _Pragma("unroll")                                                             \
    for (int nf = 0; nf < 4; ++nf)                                                \
      acc[(MH)*4+mf][nf] = mfma_bf16(af[mf], bfr[nf], acc[(MH)*4+mf][nf]);        \
  __builtin_amdgcn_s_setprio(0);                                                  \
  if (WAITV) VM4;                                                                 \
  if (DOBAR) BARX;                                                                \
} while (0)

template <typename OutT>
__global__ __launch_bounds__(512, 2) void gemm256_kernel(
    const u16* __restrict__ A,
    const u16* __restrict__ B0, const u16* __restrict__ B1, const u16* __restrict__ B2,
    OutT* __restrict__ C0, OutT* __restrict__ C1, OutT* __restrict__ C2,
    int Nd, int Kd) {
  __shared__ __align__(16) char Asb[65536];
  __shared__ __align__(16) char Bsb[65536];
  int tid = threadIdx.x;
  int wave = tid >> 6, lane = tid & 63;
  int li = lane & 15, lg = lane >> 4;
  int wr = wave >> 2, wc = wave & 3;           // 2 x 4 wave grid
  int w  = (int)blockIdx.x >> 8;               // matrix select (fused QKV)
  int tb = (int)blockIdx.x & 255;
  const u16* Bw = (w == 0) ? B0 : (w == 1) ? B1 : B2;
  OutT*      C  = (w == 0) ? C0 : (w == 1) ? C1 : C2;
  int NTn = Nd >> 8;
  int swz = (tb & 7) * 32 + (tb >> 3);         // XCD swizzle over 256 tiles
  int m0 = (swz / NTn) << 8, n0 = (swz % NTn) << 8;

  int rswz = (lg * 16) ^ (((li >> 1) & 3) << 4);
  int arow = (wr * 128 + li) * 64 + rswz;
  int brow = (wc *  64 + li) * 64 + rswz;

  int srow = wave * 16 + (lane >> 2);
  int scswz = ((lane & 3) * 16) ^ (((srow >> 1) & 3) << 4);
  size_t rowB = (size_t)Kd * 2;
  const char* Asrc = (const char*)A  + (size_t)(m0 + srow) * rowB + scswz;
  const char* Bsrc = (const char*)Bw + (size_t)(n0 + srow) * rowB + scswz;
  char* Adst = Asb + wave * 1024;
  char* Bdst = Bsb + wave * 1024;
  size_t half2 = rowB << 7;

  auto stageA = [&](int buf, int ks, int tile) {
    const char* s = Asrc + (size_t)tile * 128 + ks * 64;
    char* d = Adst + buf * 32768 + ks * 16384;
    gld16(s, d);
    gld16(s + half2, d + 8192);
  };
  auto stageB = [&](int buf, int ks, int tile) {
    const char* s = Bsrc + (size_t)tile * 128 + ks * 64;
    char* d = Bdst + buf * 32768 + ks * 16384;
    gld16(s, d);
    gld16(s + half2, d + 8192);
  };

  f32x4 acc[8][4] = {};
  bf16x8 bfr[4];

  int NKT = Kd >> 6;
  int NIT = NKT >> 1;

  stageA(0, 0, 0); stageA(0, 1, 0); stageB(0, 0, 0); stageB(0, 1, 0);
  stageA(1, 0, 1); stageB(1, 0, 1);
  asm volatile("s_waitcnt vmcnt(4)" ::: "memory");
  __builtin_amdgcn_sched_barrier(0);
  BARX;

  for (int j = 0; j < NIT; ++j) {
    int t1  = 2*j + 1;
    int tn0 = (2*j + 2) & (NKT - 1);
    int tn1 = (2*j + 3) & (NKT - 1);
    GP(0, 0, 0, true,  false, false, { stageA(1, 1, t1);  });
    GP(0, 0, 1, false, false, true,  { stageB(1, 1, t1);  });
    GP(0, 1, 1, true,  false, false, { stageA(0, 0, tn0); });
    GP(0, 1, 0, false, true,  true,  { stageB(0, 0, tn0); });
    GP(1, 0, 0, true,  false, false, { stageA(0, 1, tn0); });
    GP(1, 0, 1, false, false, true,  { stageB(0, 1, tn0); });
    GP(1, 1, 1, true,  false, false, { stageA(1, 0, tn1); });
    GP(1, 1, 0, false, true,  true,  { stageB(1, 0, tn1); });
  }
  asm volatile("s_waitcnt vmcnt(0)" ::: "memory");

  int rbase = m0 + wr*128 + lg*4;
  int cbase = n0 + wc*64 + li;
#pragma unroll
  for (int am = 0; am < 8; ++am)
#pragma unroll
    for (int nf = 0; nf < 4; ++nf)
#pragma unroll
      for (int r = 0; r < 4; ++r) {
        size_t off = (size_t)(rbase + am*16 + r) * Nd + (cbase + nf*16);
        if constexpr (sizeof(OutT) == 2) C[off] = f2bf(acc[am][nf][r]);
        else                             C[off] = acc[am][nf][r];
      }
}

// ---------------- causal flash attention, 32x32 swapped-QK^T ----------------
// R16: single-state (R14 structure, 112 VGPR — R15's dual-state spilled).
// Load balance via DISPATCH-PAIRING REMAP: with 512 blocks / 2-per-CU, the
// command processor fills CU i with block i and block i+256 (y and y+4 in a
// (64,8) grid).  qt(y) = y<4 ? 7-y : y-4 makes each CU's resident pair sum
// to exactly 36 kv-steps (was: equal-qt pairs -> 8..64 steps per CU, makespan
// set by the (7,7) CUs).  Heuristic only — correctness order-independent.
__global__ __launch_bounds__(512, 2) void flash_attn_kernel(
    const u16* __restrict__ Q, const u16* __restrict__ K, const u16* __restrict__ V,
    u16* __restrict__ O) {
  __shared__ __align__(16) u16 Ks[2*64*128];  // 32 KB swizzled [kv][dh]
  __shared__ __align__(16) u16 Vt[2*128*64];  // 32 KB swizzled [dh][kv]
  int tid = threadIdx.x, wv = tid >> 6, lane = tid & 63;
  int ql = lane & 31, hi = lane >> 5;
  int b = blockIdx.x >> 4, h = blockIdx.x & 15;
  int y = (int)blockIdx.y;
  int qt = (y < 4) ? (7 - y) : (y - 4);   // pairing remap: qt(y)+qt(y+4)=7
  int q0 = qt << 8;
  int qw = q0 + wv*32;          // wave q base
  int qa = qw + ql;             // this lane's q row
  int swzl = (ql & 7) << 4;     // Ks swizzle (256-B rows)
  int vswz = ((ql >> 1) & 7) << 4;  // Vt read swizzle (128-B rows, bits 1..3)
  const float qscale = 0.08838834764831845f * 1.4426950408889634f; // /sqrt(128)*log2e

  bf16x8 qf[8];
  {
    const u16* qp = Q + (size_t)(b*NS + qa) * ND + h*NDH + hi*8;
#pragma unroll
    for (int ds = 0; ds < 8; ++ds) {
      u16x8 t = *(const u16x8*)(qp + ds*16);
      u16x8 r;
#pragma unroll
      for (int j = 0; j < 8; ++j) r[j] = f2bf(bf2f(t[j]) * qscale);
      qf[ds] = *(bf16x8*)&r;
    }
  }
  f32x16 o0 = {}, o1 = {}, o2 = {}, o3 = {};   // O dh-subtiles 0..3
  float m_run = -INFINITY, l_run = 0.f;

  const char* Kg = (const char*)(K + (size_t)b*NS*ND + h*NDH);
  const char* Vg = (const char*)(V + (size_t)b*NS*ND + h*NDH);
  const int ROWB = ND * 2;

  int p   = tid & 31;    // dh pair for V repack
  int kvg = tid >> 5;    // kv chunk 0..15 (4 kv rows each)

  auto issueKV = [&](int kv0, int buf, unsigned (&dlo)[4], unsigned (&dhi)[4]) {
    const char* vrow = Vg + (size_t)(kv0 + kvg*4) * ROWB;
#pragma unroll
    for (int j = 0; j < 4; ++j) {
      dlo[j] = *(const unsigned*)(vrow + j*ROWB + p*4);
      dhi[j] = *(const unsigned*)(vrow + j*ROWB + 128 + p*4);
    }
    char* ksb = (char*)Ks + buf*16384;
#pragma unroll
    for (int c = 0; c < 2; ++c) {
      int s = c*8192 + wv*1024 + lane*16;
      int row = s >> 8;
      int within = (s & 255) ^ ((row & 7) << 4);
      gld16(Kg + (size_t)(kv0 + row)*ROWB + within, ksb + c*8192 + wv*1024);
    }
    __builtin_amdgcn_sched_barrier(0);
  };

  auto dostep = [&](int kv0, int buf, const unsigned (&dlo)[4], const unsigned (&dhi)[4],
                    bool hasNext) {
    if (hasNext) asm volatile("s_waitcnt vmcnt(10)" ::: "memory");
    else         asm volatile("s_waitcnt vmcnt(0)"  ::: "memory");
    __builtin_amdgcn_sched_barrier(0);
    __builtin_amdgcn_s_barrier();        // BAR-A: all waves' K(t) landed
    __builtin_amdgcn_sched_barrier(0);

    char* vtb = (char*)Vt + buf*16384;
    const char* ksb = (const char*)Ks + buf*16384;

    // Vt write: rows {2p,2p+1,2p+64,2p+65} all swizzle to granule p&7
    {
      u16x4 rA, rB, rC, rD;
#pragma unroll
      for (int j = 0; j < 4; ++j) {
        rA[j] = (u16)dlo[j]; rB[j] = (u16)(dlo[j] >> 16);
        rC[j] = (u16)dhi[j]; rD[j] = (u16)(dhi[j] >> 16);
      }
      int ws = (p & 7) << 4;
      *(u16x4*)(vtb + (((2*p   )*128 + kvg*8) ^ ws)) = rA;
      *(u16x4*)(vtb + (((2*p+ 1)*128 + kvg*8) ^ ws)) = rB;
      *(u16x4*)(vtb + (((2*p+64)*128 + kvg*8) ^ ws)) = rC;
      *(u16x4*)(vtb + (((2*p+65)*128 + kvg*8) ^ ws)) = rD;
    }

    // S = K Q^T (swapped): p0 = kv 0..31, p1 = kv 32..63; lane's q = ql
    f32x16 p0 = {}, p1 = {};
    __builtin_amdgcn_s_setprio(1);
#pragma unroll
    for (int ds = 0; ds < 8; ++ds) {
      bf16x8 kf0 = *(const bf16x8*)(ksb + ((ql*256 + ds*32 + hi*16) ^ swzl));
      p0 = mfma32_bf16(kf0, qf[ds], p0);
      bf16x8 kf1 = *(const bf16x8*)(ksb + (((32+ql)*256 + ds*32 + hi*16) ^ swzl));
      p1 = mfma32_bf16(kf1, qf[ds], p1);
    }
    __builtin_amdgcn_s_setprio(0);

    // causal mask
    if (kv0 + 63 > qw) {
      int thresh = qa - kv0 - 4*hi;
#pragma unroll
      for (int r = 0; r < 16; ++r) {
        int c0 = (r & 3) + 8*(r >> 2);
        p0[r] = (c0      > thresh) ? -INFINITY : p0[r];
        p1[r] = (c0 + 32 > thresh) ? -INFINITY : p1[r];
      }
    }

    // row max (in-reg tree + one cross-pair shuffle)
    float mx[16];
#pragma unroll
    for (int r = 0; r < 16; ++r) mx[r] = fmaxf(p0[r], p1[r]);
#pragma unroll
    for (int s = 8; s > 0; s >>= 1)
#pragma unroll
      for (int r = 0; r < 8; ++r) if (r < s) mx[r] = fmaxf(mx[r], mx[r + s]);
    float pmax = fmaxf(mx[0], __shfl_xor(mx[0], 32, 64));

    // T13 defer-max
    if (!__all(pmax <= m_run + 8.f)) {
      float mn = fmaxf(m_run, pmax);
      float corr = __builtin_amdgcn_exp2f(m_run - mn);
      m_run = mn; l_run *= corr;
#pragma unroll
      for (int r = 0; r < 16; ++r) {
        float cw = __shfl(corr, (r & 3) + 8*(r >> 2) + 4*hi, 64);
        o0[r] *= cw; o1[r] *= cw; o2[r] *= cw; o3[r] *= cw;
      }
    }

    // exp2 + row sum
    float sm[16];
#pragma unroll
    for (int r = 0; r < 16; ++r) {
      p0[r] = __builtin_amdgcn_exp2f(p0[r] - m_run);
      p1[r] = __builtin_amdgcn_exp2f(p1[r] - m_run);
      sm[r] = p0[r] + p1[r];
    }
#pragma unroll
    for (int s = 8; s > 0; s >>= 1)
#pragma unroll
      for (int r = 0; r < 8; ++r) if (r < s) sm[r] += sm[r + s];
    l_run += sm[0] + __shfl_xor(sm[0], 32, 64);

    // P -> bf16 A-frags: 16 cvt_pk + 8 permlane32_swap (T12)
    bf16x8 pa0, pa1, pa2, pa3;
#define MKPA(P, B, OUT) {                              \
      unsigned a0 = cvtpk(P[(B)+0], P[(B)+1]);         \
      unsigned b0 = cvtpk(P[(B)+4], P[(B)+5]);         \
      p32swap(a0, b0);                                 \
      unsigned a1 = cvtpk(P[(B)+2], P[(B)+3]);         \
      unsigned b1 = cvtpk(P[(B)+6], P[(B)+7]);         \
      p32swap(a1, b1);                                 \
      u32x4_t w; w[0]=a0; w[1]=a1; w[2]=b0; w[3]=b1;   \
      OUT = *(bf16x8*)&w; }
    MKPA(p0, 0, pa0)
    MKPA(p0, 8, pa1)
    MKPA(p1, 0, pa2)
    MKPA(p1, 8, pa3)
#undef MKPA

    asm volatile("s_waitcnt lgkmcnt(0)" ::: "memory");  // my Vt writes done
    __builtin_amdgcn_sched_barrier(0);
    __builtin_amdgcn_s_barrier();        // BAR-B: all waves' Vt[buf] visible
    __builtin_amdgcn_sched_barrier(0);

    // O += P V
    __builtin_amdgcn_s_setprio(1);
#define PVT(OT, T) {                                                        \
      _Pragma("unroll")                                                     \
      for (int ks = 0; ks < 4; ++ks) {                                      \
        int a = ((((T)*32 + ql)*128 + ks*32 + hi*16) ^ vswz);               \
        bf16x8 vf = *(const bf16x8*)(vtb + a);                              \
        OT = mfma32_bf16(ks==0?pa0:ks==1?pa1:ks==2?pa2:pa3, vf, OT);        \
      } }
    PVT(o0, 0)
    PVT(o1, 1)
    PVT(o2, 2)
    PVT(o3, 3)
#undef PVT
    __builtin_amdgcn_s_setprio(0);
  };

  int nt = 4*qt + 4;                     // kv tiles 0 .. q0+255
  unsigned dloA[4], dhiA[4], dloB[4], dhiB[4];
  issueKV(0, 0, dloA, dhiA);
  for (int t = 0; ; t += 2) {
    bool h1 = (t+1 < nt);
    if (h1) issueKV((t+1)*64, 1, dloB, dhiB);
    dostep(t*64, 0, dloA, dhiA, h1);
    if (!h1) break;
    bool h2 = (t+2 < nt);
    if (h2) issueKV((t+2)*64, 0, dloA, dhiA);
    dostep((t+1)*64, 1, dloB, dhiB, h2);
    if (!h2) break;
  }

  // epilogue
  float inv = 1.0f / l_run;
#pragma unroll
  for (int r = 0; r < 16; ++r) {
    int crow = (r & 3) + 8*(r >> 2) + 4*hi;
    float iv = __shfl(inv, crow, 64);
    size_t base = (size_t)(b*NS + qw + crow) * ND + h*NDH + ql;
    O[base +  0] = f2bf(o0[r] * iv);
    O[base + 32] = f2bf(o1[r] * iv);
    O[base + 64] = f2bf(o2[r] * iv);
    O[base + 96] = f2bf(o3[r] * iv);
  }
}

// ---------------- launch ----------------
extern "C" void kernel_launch(void* const* d_in, const int* in_sizes, int n_in,
                              void* d_out, int out_size, void* d_ws, size_t ws_size,
                              hipStream_t stream) {
  const float* x  = (const float*)d_in[0];
  // d_in[1] = attn_mask (causal, handled analytically)
  const float* Wq = (const float*)d_in[2];
  const float* Wk = (const float*)d_in[3];
  const float* Wv = (const float*)d_in[4];
  const float* Wo = (const float*)d_in[5];

  char* ws = (char*)d_ws;
  const size_t SZ_MD = (size_t)NM * ND * 2;
  const size_t SZ_W  = (size_t)ND * ND * 2;
  u16* xb  = (u16*)(ws);
  u16* Qb  = (u16*)(ws + SZ_MD);
  u16* Kb  = (u16*)(ws + 2*SZ_MD);
  u16* Vb  = (u16*)(ws + 3*SZ_MD);
  u16* Ab  = (u16*)(ws + 4*SZ_MD);
  u16* Wqb = (u16*)(ws + 5*SZ_MD);
  u16* Wkb = (u16*)(ws + 5*SZ_MD + SZ_W);
  u16* Wvb = (u16*)(ws + 5*SZ_MD + 2*SZ_W);
  u16* Wob = (u16*)(ws + 5*SZ_MD + 3*SZ_W);
  float* cosT = (float*)(ws + 5*SZ_MD + 4*SZ_W);
  float* sinT = (float*)(ws + 5*SZ_MD + 4*SZ_W + (size_t)NS*64*4);
  size_t needed = 5*SZ_MD + 4*SZ_W + 2*(size_t)NS*64*4;
  if (ws_size < needed) return;

  {
    int n8 = (NM * ND) / 8;
    cvt_bf16_kernel<<<(n8 + 255)/256, 256, 0, stream>>>(x, xb, n8);
    int w8 = (ND * ND) / 8;
    cvt4_bf16_kernel<<<(4*w8 + 255)/256, 256, 0, stream>>>(Wq, Wk, Wv, Wo,
                                                           Wqb, Wkb, Wvb, Wob, w8);
  }
  rope_tables_kernel<<<NS, 64, 0, stream>>>(cosT, sinT);

  // fused QKV projection: one dispatch, 768 blocks
  gemm256_kernel<u16><<<3*256, 512, 0, stream>>>(xb, Wqb, Wkb, Wvb,
                                                 Qb, Kb, Vb, ND, ND);

  {
    int nthr = NM * NH * 8;
    rope_apply_kernel<<<(2*nthr)/256, 256, 0, stream>>>(Qb, Kb, cosT, sinT, nthr);
  }

  flash_attn_kernel<<<dim3(NB*NH, NS/256), 512, 0, stream>>>(Qb, Kb, Vb, Ab);

  gemm256_kernel<float><<<256, 512, 0, stream>>>(Ab, Wob, nullptr, nullptr,
                                                 (float*)d_out, nullptr, nullptr, ND, ND);
}

// Round 17
// 409.127 us; speedup vs baseline: 1.7633x; 1.0381x over previous
//
#include <hip/hip_runtime.h>
#include <cstdint>
#include <cmath>

#define NB 4
#define NS 2048
#define ND 2048
#define NH 16
#define NDH 128
#define NM (NB*NS)   // 8192

typedef unsigned short u16;
typedef __bf16 bf16x8 __attribute__((ext_vector_type(8)));
typedef u16    u16x8  __attribute__((ext_vector_type(8)));
typedef u16    u16x4  __attribute__((ext_vector_type(4)));
typedef float  f32x4  __attribute__((ext_vector_type(4)));
typedef float  f32x16 __attribute__((ext_vector_type(16)));
typedef unsigned u32x4_t __attribute__((ext_vector_type(4)));

__device__ __forceinline__ u16 f2bf(float f) {
  unsigned u = __float_as_uint(f);
  u += 0x7fffu + ((u >> 16) & 1u);   // RNE
  return (u16)(u >> 16);
}
__device__ __forceinline__ float bf2f(u16 h) {
  return __uint_as_float(((unsigned)h) << 16);
}
__device__ __forceinline__ void gld16(const void* g, void* l) {
  __builtin_amdgcn_global_load_lds((__attribute__((address_space(1))) void*)g,
                                   (__attribute__((address_space(3))) void*)l,
                                   16, 0, 0);
}
__device__ __forceinline__ f32x4 mfma_bf16(bf16x8 a, bf16x8 b, f32x4 c) {
  return __builtin_amdgcn_mfma_f32_16x16x32_bf16(a, b, c, 0, 0, 0);
}
__device__ __forceinline__ f32x16 mfma32_bf16(bf16x8 a, bf16x8 b, f32x16 c) {
  return __builtin_amdgcn_mfma_f32_32x32x16_bf16(a, b, c, 0, 0, 0);
}
__device__ __forceinline__ unsigned cvtpk(float lo, float hi) {
  unsigned r;
  asm("v_cvt_pk_bf16_f32 %0, %1, %2" : "=v"(r) : "v"(lo), "v"(hi));
  return r;
}
__device__ __forceinline__ void p32swap(unsigned &a, unsigned &b) {
  asm volatile("v_permlane32_swap_b32 %0, %1" : "+v"(a), "+v"(b));
}

// ---------------- fp32 -> bf16 convert: x + 4 weights, ONE dispatch --------
// chunks: [0, n8x) = x ; then 4 weight matrices of n8w each.
__global__ void cvt5_bf16_kernel(const float* __restrict__ ix,
                                 const float* __restrict__ i0, const float* __restrict__ i1,
                                 const float* __restrict__ i2, const float* __restrict__ i3,
                                 u16* ox, u16* o0, u16* o1, u16* o2, u16* o3,
                                 int n8x, int n8w) {
  int idx = blockIdx.x * 256 + threadIdx.x;
  const float* in;
  u16* out;
  int i;
  if (idx < n8x) { in = ix; out = ox; i = idx; }
  else {
    int r = idx - n8x;
    int w = r / n8w; i = r - w * n8w;
    if (w >= 4) return;
    in  = (w == 0) ? i0 : (w == 1) ? i1 : (w == 2) ? i2 : i3;
    out = (w == 0) ? o0 : (w == 1) ? o1 : (w == 2) ? o2 : o3;
  }
  const float4* p = (const float4*)in + (size_t)i * 2;
  float4 a = p[0], b = p[1];
  u16x8 r8;
  r8[0]=f2bf(a.x); r8[1]=f2bf(a.y); r8[2]=f2bf(a.z); r8[3]=f2bf(a.w);
  r8[4]=f2bf(b.x); r8[5]=f2bf(b.y); r8[6]=f2bf(b.z); r8[7]=f2bf(b.w);
  ((u16x8*)out)[i] = r8;
}

// ---------------- RoPE tables: cos/sin [S][64] ----------------
__global__ void rope_tables_kernel(float* __restrict__ cosT, float* __restrict__ sinT) {
  int s = blockIdx.x, d = threadIdx.x;
  double inv = pow(10000.0, -(double)d / 64.0);
  float ang = (float)((double)s * inv);
  cosT[s*64 + d] = cosf(ang);
  sinT[s*64 + d] = sinf(ang);
}

// ---------------- RoPE apply, Q and K in one dispatch ----------------
__global__ void rope_apply_kernel(u16* __restrict__ Qb, u16* __restrict__ Kb,
                                  const float* __restrict__ cosT,
                                  const float* __restrict__ sinT, int nthr) {
  int gidx = blockIdx.x * 256 + threadIdx.x;
  u16* X = (gidx < nthr) ? Qb : Kb;
  int idx = (gidx < nthr) ? gidx : gidx - nthr;
  int pc = idx & 7, h = (idx >> 3) & (NH - 1), m = idx >> 7;
  int s = m & (NS - 1);
  int d0 = pc * 8;
  size_t base = (size_t)m * ND + h * NDH + d0;
  u16x8 v0 = *(const u16x8*)(X + base);
  u16x8 v1 = *(const u16x8*)(X + base + 64);
  u16x8 r0, r1;
#pragma unroll
  for (int j = 0; j < 8; ++j) {
    float c  = cosT[s*64 + d0 + j];
    float sn = sinT[s*64 + d0 + j];
    float x0 = bf2f(v0[j]), x1 = bf2f(v1[j]);
    r0[j] = f2bf(x0 * c - x1 * sn);
    r1[j] = f2bf(x1 * c + x0 * sn);
  }
  *(u16x8*)(X + base)      = r0;
  *(u16x8*)(X + base + 64) = r1;
}

// ---------------- bf16 GEMM, 256x256 tile, 8-phase, 16x16x32 MFMA ----------
// R13 schedule (best of R8/R12/R13/R14): barriers at even phases only,
// vmcnt(4) at phases 4/8; conflict-free swizzle keyed on row bits 1..2
// (rows are 64 B so bank phase carries row bit 0; SQ_LDS_BANK_CONFLICT = 0).
#define BARX do { __builtin_amdgcn_s_barrier(); __builtin_amdgcn_sched_barrier(0); } while (0)
#define VM4  do { asm volatile("s_waitcnt vmcnt(4)" ::: "memory"); \
                  __builtin_amdgcn_sched_barrier(0); } while (0)
#define GP(BUF, KS, MH, LOADB, WAITV, DOBAR, STAGE) do {                          \
  bf16x8 af[4];                                                                   \
  _Pragma("unroll")                                                               \
  for (int mf = 0; mf < 4; ++mf)                                                  \
    af[mf] = *(const bf16x8*)(Asb + (BUF)*32768 + (KS)*16384 + arow + ((MH)*4+mf)*1024); \
  if (LOADB) {                                                                    \
    _Pragma("unroll")                                                             \
    for (int nf = 0; nf < 4; ++nf)                                                \
      bfr[nf] = *(const bf16x8*)(Bsb + (BUF)*32768 + (KS)*16384 + brow + nf*1024); \
  }                                                                               \
  STAGE;                                                                          \
  __builtin_amdgcn_s_setprio(1);                                                  \
  _Pragma("unroll")                                                               \
  for (int mf = 0; mf < 4; ++mf)                                                  \
    _Pragma("unroll")                                                             \
    for (int nf = 0; nf < 4; ++nf)                                                \
      acc[(MH)*4+mf][nf] = mfma_bf16(af[mf], bfr[nf], acc[(MH)*4+mf][nf]);        \
  __builtin_amdgcn_s_setprio(0);                                                  \
  if (WAITV) VM4;                                                                 \
  if (DOBAR) BARX;                                                                \
} while (0)

template <typename OutT>
__global__ __launch_bounds__(512, 2) void gemm256_kernel(
    const u16* __restrict__ A,
    const u16* __restrict__ B0, const u16* __restrict__ B1, const u16* __restrict__ B2,
    OutT* __restrict__ C0, OutT* __restrict__ C1, OutT* __restrict__ C2,
    int Nd, int Kd) {
  __shared__ __align__(16) char Asb[65536];
  __shared__ __align__(16) char Bsb[65536];
  int tid = threadIdx.x;
  int wave = tid >> 6, lane = tid & 63;
  int li = lane & 15, lg = lane >> 4;
  int wr = wave >> 2, wc = wave & 3;           // 2 x 4 wave grid
  int w  = (int)blockIdx.x >> 8;               // matrix select (fused QKV)
  int tb = (int)blockIdx.x & 255;
  const u16* Bw = (w == 0) ? B0 : (w == 1) ? B1 : B2;
  OutT*      C  = (w == 0) ? C0 : (w == 1) ? C1 : C2;
  int NTn = Nd >> 8;
  int swz = (tb & 7) * 32 + (tb >> 3);         // XCD swizzle over 256 tiles
  int m0 = (swz / NTn) << 8, n0 = (swz % NTn) << 8;

  int rswz = (lg * 16) ^ (((li >> 1) & 3) << 4);
  int arow = (wr * 128 + li) * 64 + rswz;
  int brow = (wc *  64 + li) * 64 + rswz;

  int srow = wave * 16 + (lane >> 2);
  int scswz = ((lane & 3) * 16) ^ (((srow >> 1) & 3) << 4);
  size_t rowB = (size_t)Kd * 2;
  const char* Asrc = (const char*)A  + (size_t)(m0 + srow) * rowB + scswz;
  const char* Bsrc = (const char*)Bw + (size_t)(n0 + srow) * rowB + scswz;
  char* Adst = Asb + wave * 1024;
  char* Bdst = Bsb + wave * 1024;
  size_t half2 = rowB << 7;

  auto stageA = [&](int buf, int ks, int tile) {
    const char* s = Asrc + (size_t)tile * 128 + ks * 64;
    char* d = Adst + buf * 32768 + ks * 16384;
    gld16(s, d);
    gld16(s + half2, d + 8192);
  };
  auto stageB = [&](int buf, int ks, int tile) {
    const char* s = Bsrc + (size_t)tile * 128 + ks * 64;
    char* d = Bdst + buf * 32768 + ks * 16384;
    gld16(s, d);
    gld16(s + half2, d + 8192);
  };

  f32x4 acc[8][4] = {};
  bf16x8 bfr[4];

  int NKT = Kd >> 6;
  int NIT = NKT >> 1;

  stageA(0, 0, 0); stageA(0, 1, 0); stageB(0, 0, 0); stageB(0, 1, 0);
  stageA(1, 0, 1); stageB(1, 0, 1);
  asm volatile("s_waitcnt vmcnt(4)" ::: "memory");
  __builtin_amdgcn_sched_barrier(0);
  BARX;

  for (int j = 0; j < NIT; ++j) {
    int t1  = 2*j + 1;
    int tn0 = (2*j + 2) & (NKT - 1);
    int tn1 = (2*j + 3) & (NKT - 1);
    GP(0, 0, 0, true,  false, false, { stageA(1, 1, t1);  });
    GP(0, 0, 1, false, false, true,  { stageB(1, 1, t1);  });
    GP(0, 1, 1, true,  false, false, { stageA(0, 0, tn0); });
    GP(0, 1, 0, false, true,  true,  { stageB(0, 0, tn0); });
    GP(1, 0, 0, true,  false, false, { stageA(0, 1, tn0); });
    GP(1, 0, 1, false, false, true,  { stageB(0, 1, tn0); });
    GP(1, 1, 1, true,  false, false, { stageA(1, 0, tn1); });
    GP(1, 1, 0, false, true,  true,  { stageB(1, 0, tn1); });
  }
  asm volatile("s_waitcnt vmcnt(0)" ::: "memory");

  int rbase = m0 + wr*128 + lg*4;
  int cbase = n0 + wc*64 + li;
#pragma unroll
  for (int am = 0; am < 8; ++am)
#pragma unroll
    for (int nf = 0; nf < 4; ++nf)
#pragma unroll
      for (int r = 0; r < 4; ++r) {
        size_t off = (size_t)(rbase + am*16 + r) * Nd + (cbase + nf*16);
        if constexpr (sizeof(OutT) == 2) C[off] = f2bf(acc[am][nf][r]);
        else                             C[off] = acc[am][nf][r];
      }
}

// ---------------- causal flash attention, 32x32 swapped-QK^T ----------------
// R17 = R13 attn exactly: single state, heavy q-tiles dispatch first
// (greedy backfill self-balances; R15 dual-state spilled, R16 remap was
// slightly negative — dispatch does not pair i with i+256).
__global__ __launch_bounds__(512, 2) void flash_attn_kernel(
    const u16* __restrict__ Q, const u16* __restrict__ K, const u16* __restrict__ V,
    u16* __restrict__ O) {
  __shared__ __align__(16) u16 Ks[2*64*128];  // 32 KB swizzled [kv][dh]
  __shared__ __align__(16) u16 Vt[2*128*64];  // 32 KB swizzled [dh][kv]
  int tid = threadIdx.x, wv = tid >> 6, lane = tid & 63;
  int ql = lane & 31, hi = lane >> 5;
  int b = blockIdx.x >> 4, h = blockIdx.x & 15;
  int qt = (int)gridDim.y - 1 - (int)blockIdx.y;   // heavy first
  int q0 = qt << 8;
  int qw = q0 + wv*32;          // wave q base
  int qa = qw + ql;             // this lane's q row
  int swzl = (ql & 7) << 4;     // Ks swizzle (256-B rows)
  int vswz = ((ql >> 1) & 7) << 4;  // Vt read swizzle (128-B rows, bits 1..3)
  const float qscale = 0.08838834764831845f * 1.4426950408889634f; // /sqrt(128)*log2e

  bf16x8 qf[8];
  {
    const u16* qp = Q + (size_t)(b*NS + qa) * ND + h*NDH + hi*8;
#pragma unroll
    for (int ds = 0; ds < 8; ++ds) {
      u16x8 t = *(const u16x8*)(qp + ds*16);
      u16x8 r;
#pragma unroll
      for (int j = 0; j < 8; ++j) r[j] = f2bf(bf2f(t[j]) * qscale);
      qf[ds] = *(bf16x8*)&r;
    }
  }
  f32x16 o0 = {}, o1 = {}, o2 = {}, o3 = {};   // O dh-subtiles 0..3
  float m_run = -INFINITY, l_run = 0.f;

  const char* Kg = (const char*)(K + (size_t)b*NS*ND + h*NDH);
  const char* Vg = (const char*)(V + (size_t)b*NS*ND + h*NDH);
  const int ROWB = ND * 2;

  int p   = tid & 31;    // dh pair for V repack
  int kvg = tid >> 5;    // kv chunk 0..15 (4 kv rows each)

  auto issueKV = [&](int kv0, int buf, unsigned (&dlo)[4], unsigned (&dhi)[4]) {
    const char* vrow = Vg + (size_t)(kv0 + kvg*4) * ROWB;
#pragma unroll
    for (int j = 0; j < 4; ++j) {
      dlo[j] = *(const unsigned*)(vrow + j*ROWB + p*4);
      dhi[j] = *(const unsigned*)(vrow + j*ROWB + 128 + p*4);
    }
    char* ksb = (char*)Ks + buf*16384;
#pragma unroll
    for (int c = 0; c < 2; ++c) {
      int s = c*8192 + wv*1024 + lane*16;
      int row = s >> 8;
      int within = (s & 255) ^ ((row & 7) << 4);
      gld16(Kg + (size_t)(kv0 + row)*ROWB + within, ksb + c*8192 + wv*1024);
    }
    __builtin_amdgcn_sched_barrier(0);
  };

  auto dostep = [&](int kv0, int buf, const unsigned (&dlo)[4], const unsigned (&dhi)[4],
                    bool hasNext) {
    if (hasNext) asm volatile("s_waitcnt vmcnt(10)" ::: "memory");
    else         asm volatile("s_waitcnt vmcnt(0)"  ::: "memory");
    __builtin_amdgcn_sched_barrier(0);
    __builtin_amdgcn_s_barrier();        // BAR-A: all waves' K(t) landed
    __builtin_amdgcn_sched_barrier(0);

    char* vtb = (char*)Vt + buf*16384;
    const char* ksb = (const char*)Ks + buf*16384;

    // Vt write: rows {2p,2p+1,2p+64,2p+65} all swizzle to granule p&7
    {
      u16x4 rA, rB, rC, rD;
#pragma unroll
      for (int j = 0; j < 4; ++j) {
        rA[j] = (u16)dlo[j]; rB[j] = (u16)(dlo[j] >> 16);
        rC[j] = (u16)dhi[j]; rD[j] = (u16)(dhi[j] >> 16);
      }
      int ws = (p & 7) << 4;
      *(u16x4*)(vtb + (((2*p   )*128 + kvg*8) ^ ws)) = rA;
      *(u16x4*)(vtb + (((2*p+ 1)*128 + kvg*8) ^ ws)) = rB;
      *(u16x4*)(vtb + (((2*p+64)*128 + kvg*8) ^ ws)) = rC;
      *(u16x4*)(vtb + (((2*p+65)*128 + kvg*8) ^ ws)) = rD;
    }

    // S = K Q^T (swapped): p0 = kv 0..31, p1 = kv 32..63; lane's q = ql
    f32x16 p0 = {}, p1 = {};
    __builtin_amdgcn_s_setprio(1);
#pragma unroll
    for (int ds = 0; ds < 8; ++ds) {
      bf16x8 kf0 = *(const bf16x8*)(ksb + ((ql*256 + ds*32 + hi*16) ^ swzl));
      p0 = mfma32_bf16(kf0, qf[ds], p0);
      bf16x8 kf1 = *(const bf16x8*)(ksb + (((32+ql)*256 + ds*32 + hi*16) ^ swzl));
      p1 = mfma32_bf16(kf1, qf[ds], p1);
    }
    __builtin_amdgcn_s_setprio(0);

    // causal mask
    if (kv0 + 63 > qw) {
      int thresh = qa - kv0 - 4*hi;
#pragma unroll
      for (int r = 0; r < 16; ++r) {
        int c0 = (r & 3) + 8*(r >> 2);
        p0[r] = (c0      > thresh) ? -INFINITY : p0[r];
        p1[r] = (c0 + 32 > thresh) ? -INFINITY : p1[r];
      }
    }

    // row max (in-reg tree + one cross-pair shuffle)
    float mx[16];
#pragma unroll
    for (int r = 0; r < 16; ++r) mx[r] = fmaxf(p0[r], p1[r]);
#pragma unroll
    for (int s = 8; s > 0; s >>= 1)
#pragma unroll
      for (int r = 0; r < 8; ++r) if (r < s) mx[r] = fmaxf(mx[r], mx[r + s]);
    float pmax = fmaxf(mx[0], __shfl_xor(mx[0], 32, 64));

    // T13 defer-max
    if (!__all(pmax <= m_run + 8.f)) {
      float mn = fmaxf(m_run, pmax);
      float corr = __builtin_amdgcn_exp2f(m_run - mn);
      m_run = mn; l_run *= corr;
#pragma unroll
      for (int r = 0; r < 16; ++r) {
        float cw = __shfl(corr, (r & 3) + 8*(r >> 2) + 4*hi, 64);
        o0[r] *= cw; o1[r] *= cw; o2[r] *= cw; o3[r] *= cw;
      }
    }

    // exp2 + row sum
    float sm[16];
#pragma unroll
    for (int r = 0; r < 16; ++r) {
      p0[r] = __builtin_amdgcn_exp2f(p0[r] - m_run);
      p1[r] = __builtin_amdgcn_exp2f(p1[r] - m_run);
      sm[r] = p0[r] + p1[r];
    }
#pragma unroll
    for (int s = 8; s > 0; s >>= 1)
#pragma unroll
      for (int r = 0; r < 8; ++r) if (r < s) sm[r] += sm[r + s];
    l_run += sm[0] + __shfl_xor(sm[0], 32, 64);

    // P -> bf16 A-frags: 16 cvt_pk + 8 permlane32_swap (T12)
    bf16x8 pa0, pa1, pa2, pa3;
#define MKPA(P, B, OUT) {                              \
      unsigned a0 = cvtpk(P[(B)+0], P[(B)+1]);         \
      unsigned b0 = cvtpk(P[(B)+4], P[(B)+5]);         \
      p32swap(a0, b0);                                 \
      unsigned a1 = cvtpk(P[(B)+2], P[(B)+3]);         \
      unsigned b1 = cvtpk(P[(B)+6], P[(B)+7]);         \
      p32swap(a1, b1);                                 \
      u32x4_t w; w[0]=a0; w[1]=a1; w[2]=b0; w[3]=b1;   \
      OUT = *(bf16x8*)&w; }
    MKPA(p0, 0, pa0)
    MKPA(p0, 8, pa1)
    MKPA(p1, 0, pa2)
    MKPA(p1, 8, pa3)
#undef MKPA

    asm volatile("s_waitcnt lgkmcnt(0)" ::: "memory");  // my Vt writes done
    __builtin_amdgcn_sched_barrier(0);
    __builtin_amdgcn_s_barrier();        // BAR-B: all waves' Vt[buf] visible
    __builtin_amdgcn_sched_barrier(0);

    // O += P V
    __builtin_amdgcn_s_setprio(1);
#define PVT(OT, T) {                                                        \
      _Pragma("unroll")                                                     \
      for (int ks = 0; ks < 4; ++ks) {                                      \
        int a = ((((T)*32 + ql)*128 + ks*32 + hi*16) ^ vswz);               \
        bf16x8 vf = *(const bf16x8*)(vtb + a);                              \
        OT = mfma32_bf16(ks==0?pa0:ks==1?pa1:ks==2?pa2:pa3, vf, OT);        \
      } }
    PVT(o0, 0)
    PVT(o1, 1)
    PVT(o2, 2)
    PVT(o3, 3)
#undef PVT
    __builtin_amdgcn_s_setprio(0);
  };

  int nt = 4*qt + 4;                     // kv tiles 0 .. q0+255
  unsigned dloA[4], dhiA[4], dloB[4], dhiB[4];
  issueKV(0, 0, dloA, dhiA);
  for (int t = 0; ; t += 2) {
    bool h1 = (t+1 < nt);
    if (h1) issueKV((t+1)*64, 1, dloB, dhiB);
    dostep(t*64, 0, dloA, dhiA, h1);
    if (!h1) break;
    bool h2 = (t+2 < nt);
    if (h2) issueKV((t+2)*64, 0, dloA, dhiA);
    dostep((t+1)*64, 1, dloB, dhiB, h2);
    if (!h2) break;
  }

  // epilogue
  float inv = 1.0f / l_run;
#pragma unroll
  for (int r = 0; r < 16; ++r) {
    int crow = (r & 3) + 8*(r >> 2) + 4*hi;
    float iv = __shfl(inv, crow, 64);
    size_t base = (size_t)(b*NS + qw + crow) * ND + h*NDH + ql;
    O[base +  0] = f2bf(o0[r] * iv);
    O[base + 32] = f2bf(o1[r] * iv);
    O[base + 64] = f2bf(o2[r] * iv);
    O[base + 96] = f2bf(o3[r] * iv);
  }
}

// ---------------- launch ----------------
extern "C" void kernel_launch(void* const* d_in, const int* in_sizes, int n_in,
                              void* d_out, int out_size, void* d_ws, size_t ws_size,
                              hipStream_t stream) {
  const float* x  = (const float*)d_in[0];
  // d_in[1] = attn_mask (causal, handled analytically)
  const float* Wq = (const float*)d_in[2];
  const float* Wk = (const float*)d_in[3];
  const float* Wv = (const float*)d_in[4];
  const float* Wo = (const float*)d_in[5];

  char* ws = (char*)d_ws;
  const size_t SZ_MD = (size_t)NM * ND * 2;
  const size_t SZ_W  = (size_t)ND * ND * 2;
  u16* xb  = (u16*)(ws);
  u16* Qb  = (u16*)(ws + SZ_MD);
  u16* Kb  = (u16*)(ws + 2*SZ_MD);
  u16* Vb  = (u16*)(ws + 3*SZ_MD);
  u16* Ab  = (u16*)(ws + 4*SZ_MD);
  u16* Wqb = (u16*)(ws + 5*SZ_MD);
  u16* Wkb = (u16*)(ws + 5*SZ_MD + SZ_W);
  u16* Wvb = (u16*)(ws + 5*SZ_MD + 2*SZ_W);
  u16* Wob = (u16*)(ws + 5*SZ_MD + 3*SZ_W);
  float* cosT = (float*)(ws + 5*SZ_MD + 4*SZ_W);
  float* sinT = (float*)(ws + 5*SZ_MD + 4*SZ_W + (size_t)NS*64*4);
  size_t needed = 5*SZ_MD + 4*SZ_W + 2*(size_t)NS*64*4;
  if (ws_size < needed) return;

  {
    int n8x = (NM * ND) / 8;          // 2,097,152
    int n8w = (ND * ND) / 8;          //   524,288
    int tot = n8x + 4 * n8w;
    cvt5_bf16_kernel<<<(tot + 255)/256, 256, 0, stream>>>(
        x, Wq, Wk, Wv, Wo, xb, Wqb, Wkb, Wvb, Wob, n8x, n8w);
  }
  rope_tables_kernel<<<NS, 64, 0, stream>>>(cosT, sinT);

  // fused QKV projection: one dispatch, 768 blocks
  gemm256_kernel<u16><<<3*256, 512, 0, stream>>>(xb, Wqb, Wkb, Wvb,
                                                 Qb, Kb, Vb, ND, ND);

  {
    int nthr = NM * NH * 8;
    rope_apply_kernel<<<(2*nthr)/256, 256, 0, stream>>>(Qb, Kb, cosT, sinT, nthr);
  }

  flash_attn_kernel<<<dim3(NB*NH, NS/256), 512, 0, stream>>>(Qb, Kb, Vb, Ab);

  gemm256_kernel<float><<<256, 512, 0, stream>>>(Ab, Wob, nullptr, nullptr,
                                                 (float*)d_out, nullptr, nullptr, ND, ND);
}

// Round 18
// 391.288 us; speedup vs baseline: 1.8437x; 1.0456x over previous
//
#include <hip/hip_runtime.h>
#include <cstdint>
#include <cmath>

#define NB 4
#define NS 2048
#define ND 2048
#define NH 16
#define NDH 128
#define NM (NB*NS)   // 8192

typedef unsigned short u16;
typedef __bf16 bf16x8 __attribute__((ext_vector_type(8)));
typedef u16    u16x8  __attribute__((ext_vector_type(8)));
typedef u16    u16x4  __attribute__((ext_vector_type(4)));
typedef float  f32x4  __attribute__((ext_vector_type(4)));
typedef float  f32x16 __attribute__((ext_vector_type(16)));
typedef unsigned u32x4_t __attribute__((ext_vector_type(4)));

__device__ __forceinline__ u16 f2bf(float f) {
  unsigned u = __float_as_uint(f);
  u += 0x7fffu + ((u >> 16) & 1u);   // RNE
  return (u16)(u >> 16);
}
__device__ __forceinline__ float bf2f(u16 h) {
  return __uint_as_float(((unsigned)h) << 16);
}
__device__ __forceinline__ void gld16(const void* g, void* l) {
  __builtin_amdgcn_global_load_lds((__attribute__((address_space(1))) void*)g,
                                   (__attribute__((address_space(3))) void*)l,
                                   16, 0, 0);
}
__device__ __forceinline__ f32x4 mfma_bf16(bf16x8 a, bf16x8 b, f32x4 c) {
  return __builtin_amdgcn_mfma_f32_16x16x32_bf16(a, b, c, 0, 0, 0);
}
__device__ __forceinline__ f32x16 mfma32_bf16(bf16x8 a, bf16x8 b, f32x16 c) {
  return __builtin_amdgcn_mfma_f32_32x32x16_bf16(a, b, c, 0, 0, 0);
}
__device__ __forceinline__ unsigned cvtpk(float lo, float hi) {
  unsigned r;
  asm("v_cvt_pk_bf16_f32 %0, %1, %2" : "=v"(r) : "v"(lo), "v"(hi));
  return r;
}
__device__ __forceinline__ void p32swap(unsigned &a, unsigned &b) {
  asm volatile("v_permlane32_swap_b32 %0, %1" : "+v"(a), "+v"(b));
}

// ---------------- fp32 -> bf16 convert: x + 4 weights, ONE dispatch --------
__global__ void cvt5_bf16_kernel(const float* __restrict__ ix,
                                 const float* __restrict__ i0, const float* __restrict__ i1,
                                 const float* __restrict__ i2, const float* __restrict__ i3,
                                 u16* ox, u16* o0, u16* o1, u16* o2, u16* o3,
                                 int n8x, int n8w) {
  int idx = blockIdx.x * 256 + threadIdx.x;
  const float* in;
  u16* out;
  int i;
  if (idx < n8x) { in = ix; out = ox; i = idx; }
  else {
    int r = idx - n8x;
    int w = r / n8w; i = r - w * n8w;
    if (w >= 4) return;
    in  = (w == 0) ? i0 : (w == 1) ? i1 : (w == 2) ? i2 : i3;
    out = (w == 0) ? o0 : (w == 1) ? o1 : (w == 2) ? o2 : o3;
  }
  const float4* p = (const float4*)in + (size_t)i * 2;
  float4 a = p[0], b = p[1];
  u16x8 r8;
  r8[0]=f2bf(a.x); r8[1]=f2bf(a.y); r8[2]=f2bf(a.z); r8[3]=f2bf(a.w);
  r8[4]=f2bf(b.x); r8[5]=f2bf(b.y); r8[6]=f2bf(b.z); r8[7]=f2bf(b.w);
  ((u16x8*)out)[i] = r8;
}

// ---------------- RoPE tables: cos/sin [S][64] ----------------
__global__ void rope_tables_kernel(float* __restrict__ cosT, float* __restrict__ sinT) {
  int s = blockIdx.x, d = threadIdx.x;
  double inv = pow(10000.0, -(double)d / 64.0);
  float ang = (float)((double)s * inv);
  cosT[s*64 + d] = cosf(ang);
  sinT[s*64 + d] = sinf(ang);
}

// ---------------- bf16 GEMM, 256x256 tile, 8-phase, 16x16x32 MFMA ----------
// R18: RoPE fused into the Q/K epilogue.  B-fragment column remap so each
// thread holds BOTH halves of a RoPE pair (d, d+64) within one head:
//   wave wc covers N-rows (wc>>1)*128 + (wc&1)*32 + {0,16} + {0,64} + li
// (bijective on [0,256); added constants are multiples of 16 so the
// bank-swizzle proof is unchanged — bits 1..2 still come from li only).
// Fragments nf and nf+2 are column partners (+64, same head).  Epilogue for
// w<2 applies RoPE on fp32 accumulators (cos/sin gathers coalesced per
// 16-lane group); V (w=2) and Wo (float) use the plain store.
// Schedule = R13 (best): barriers at even phases, vmcnt(4) at phases 4/8.
#define BARX do { __builtin_amdgcn_s_barrier(); __builtin_amdgcn_sched_barrier(0); } while (0)
#define VM4  do { asm volatile("s_waitcnt vmcnt(4)" ::: "memory"); \
                  __builtin_amdgcn_sched_barrier(0); } while (0)
#define GP(BUF, KS, MH, LOADB, WAITV, DOBAR, STAGE) do {                          \
  bf16x8 af[4];                                                                   \
  _Pragma("unroll")                                                               \
  for (int mf = 0; mf < 4; ++mf)                                                  \
    af[mf] = *(const bf16x8*)(Asb + (BUF)*32768 + (KS)*16384 + arow + ((MH)*4+mf)*1024); \
  if (LOADB) {                                                                    \
    _Pragma("unroll")                                                             \
    for (int nf = 0; nf < 4; ++nf)                                                \
      bfr[nf] = *(const bf16x8*)(Bsb + (BUF)*32768 + (KS)*16384 + brow            \
                                 + (nf & 1)*1024 + (nf >> 1)*4096);               \
  }                                                                               \
  STAGE;                                                                          \
  __builtin_amdgcn_s_setprio(1);                                                  \
  _Pragma("unroll")                                                               \
  for (int mf = 0; mf < 4; ++mf)                                                  \
    _Pragma("unroll")                                                             \
    for (int nf = 0; nf < 4; ++nf)                                                \
      acc[(MH)*4+mf][nf] = mfma_bf16(af[mf], bfr[nf], acc[(MH)*4+mf][nf]);        \
  __builtin_amdgcn_s_setprio(0);                                                  \
  if (WAITV) VM4;                                                                 \
  if (DOBAR) BARX;                                                                \
} while (0)

template <typename OutT>
__global__ __launch_bounds__(512, 2) void gemm256_kernel(
    const u16* __restrict__ A,
    const u16* __restrict__ B0, const u16* __restrict__ B1, const u16* __restrict__ B2,
    OutT* __restrict__ C0, OutT* __restrict__ C1, OutT* __restrict__ C2,
    const float* __restrict__ cosT, const float* __restrict__ sinT,
    int Nd, int Kd) {
  __shared__ __align__(16) char Asb[65536];
  __shared__ __align__(16) char Bsb[65536];
  int tid = threadIdx.x;
  int wave = tid >> 6, lane = tid & 63;
  int li = lane & 15, lg = lane >> 4;
  int wr = wave >> 2, wc = wave & 3;           // 2 x 4 wave grid
  int w  = (int)blockIdx.x >> 8;               // matrix select (fused QKV)
  int tb = (int)blockIdx.x & 255;
  const u16* Bw = (w == 0) ? B0 : (w == 1) ? B1 : B2;
  OutT*      C  = (w == 0) ? C0 : (w == 1) ? C1 : C2;
  int NTn = Nd >> 8;
  int swz = (tb & 7) * 32 + (tb >> 3);         // XCD swizzle over 256 tiles
  int m0 = (swz / NTn) << 8, n0 = (swz % NTn) << 8;

  int rswz = (lg * 16) ^ (((li >> 1) & 3) << 4);
  int arow = (wr * 128 + li) * 64 + rswz;
  // B columns: base row (wc>>1)*128 + (wc&1)*32 + li; frag nf adds
  // (nf&1)*16 + (nf>>1)*64 rows (handled in GP as byte offsets)
  int bcol0 = (wc >> 1)*128 + (wc & 1)*32;     // wave's within-tile col base
  int brow = (bcol0 + li) * 64 + rswz;

  int srow = wave * 16 + (lane >> 2);
  int scswz = ((lane & 3) * 16) ^ (((srow >> 1) & 3) << 4);
  size_t rowB = (size_t)Kd * 2;
  const char* Asrc = (const char*)A  + (size_t)(m0 + srow) * rowB + scswz;
  const char* Bsrc = (const char*)Bw + (size_t)(n0 + srow) * rowB + scswz;
  char* Adst = Asb + wave * 1024;
  char* Bdst = Bsb + wave * 1024;
  size_t half2 = rowB << 7;

  auto stageA = [&](int buf, int ks, int tile) {
    const char* s = Asrc + (size_t)tile * 128 + ks * 64;
    char* d = Adst + buf * 32768 + ks * 16384;
    gld16(s, d);
    gld16(s + half2, d + 8192);
  };
  auto stageB = [&](int buf, int ks, int tile) {
    const char* s = Bsrc + (size_t)tile * 128 + ks * 64;
    char* d = Bdst + buf * 32768 + ks * 16384;
    gld16(s, d);
    gld16(s + half2, d + 8192);
  };

  f32x4 acc[8][4] = {};
  bf16x8 bfr[4];

  int NKT = Kd >> 6;
  int NIT = NKT >> 1;

  stageA(0, 0, 0); stageA(0, 1, 0); stageB(0, 0, 0); stageB(0, 1, 0);
  stageA(1, 0, 1); stageB(1, 0, 1);
  asm volatile("s_waitcnt vmcnt(4)" ::: "memory");
  __builtin_amdgcn_sched_barrier(0);
  BARX;

  for (int j = 0; j < NIT; ++j) {
    int t1  = 2*j + 1;
    int tn0 = (2*j + 2) & (NKT - 1);
    int tn1 = (2*j + 3) & (NKT - 1);
    GP(0, 0, 0, true,  false, false, { stageA(1, 1, t1);  });
    GP(0, 0, 1, false, false, true,  { stageB(1, 1, t1);  });
    GP(0, 1, 1, true,  false, false, { stageA(0, 0, tn0); });
    GP(0, 1, 0, false, true,  true,  { stageB(0, 0, tn0); });
    GP(1, 0, 0, true,  false, false, { stageA(0, 1, tn0); });
    GP(1, 0, 1, false, false, true,  { stageB(0, 1, tn0); });
    GP(1, 1, 1, true,  false, false, { stageA(1, 0, tn1); });
    GP(1, 1, 0, false, true,  true,  { stageB(1, 0, tn1); });
  }
  asm volatile("s_waitcnt vmcnt(0)" ::: "memory");

  // epilogue: C row = rbase + am*16 + r; col = n0 + bcol0 + (nf&1)*16
  //           + (nf>>1)*64 + li  [C/D map m89/m91]
  int rbase = m0 + wr*128 + lg*4;
  int cbase = n0 + bcol0 + li;
  if constexpr (sizeof(OutT) == 2) {
    if (w < 2) {
      // RoPE on fp32 acc: pair (nf2, nf2+2) = (d, d+64) within one head
      int dbase = (wc & 1)*32 + li;          // within-head d, [0,64)
#pragma unroll
      for (int am = 0; am < 8; ++am)
#pragma unroll
        for (int r = 0; r < 4; ++r) {
          int grow = rbase + am*16 + r;
          int s = grow & (NS - 1);
          const float* cp = cosT + s*64 + dbase;
          const float* sp = sinT + s*64 + dbase;
#pragma unroll
          for (int nf2 = 0; nf2 < 2; ++nf2) {
            float c  = cp[nf2*16];
            float sn = sp[nf2*16];
            float v0 = acc[am][nf2][r];
            float v1 = acc[am][nf2+2][r];
            size_t off = (size_t)grow * Nd + (cbase + nf2*16);
            C[off]      = f2bf(v0*c - v1*sn);
            C[off + 64] = f2bf(v1*c + v0*sn);
          }
        }
    } else {
#pragma unroll
      for (int am = 0; am < 8; ++am)
#pragma unroll
        for (int nf = 0; nf < 4; ++nf)
#pragma unroll
          for (int r = 0; r < 4; ++r) {
            size_t off = (size_t)(rbase + am*16 + r) * Nd
                         + (cbase + (nf & 1)*16 + (nf >> 1)*64);
            C[off] = f2bf(acc[am][nf][r]);
          }
    }
  } else {
#pragma unroll
    for (int am = 0; am < 8; ++am)
#pragma unroll
      for (int nf = 0; nf < 4; ++nf)
#pragma unroll
        for (int r = 0; r < 4; ++r) {
          size_t off = (size_t)(rbase + am*16 + r) * Nd
                       + (cbase + (nf & 1)*16 + (nf >> 1)*64);
          C[off] = acc[am][nf][r];
        }
  }
}

// ---------------- causal flash attention, 32x32 swapped-QK^T ----------------
// R17/R13 attn: single state, heavy q-tiles dispatch first.
__global__ __launch_bounds__(512, 2) void flash_attn_kernel(
    const u16* __restrict__ Q, const u16* __restrict__ K, const u16* __restrict__ V,
    u16* __restrict__ O) {
  __shared__ __align__(16) u16 Ks[2*64*128];  // 32 KB swizzled [kv][dh]
  __shared__ __align__(16) u16 Vt[2*128*64];  // 32 KB swizzled [dh][kv]
  int tid = threadIdx.x, wv = tid >> 6, lane = tid & 63;
  int ql = lane & 31, hi = lane >> 5;
  int b = blockIdx.x >> 4, h = blockIdx.x & 15;
  int qt = (int)gridDim.y - 1 - (int)blockIdx.y;   // heavy first
  int q0 = qt << 8;
  int qw = q0 + wv*32;          // wave q base
  int qa = qw + ql;             // this lane's q row
  int swzl = (ql & 7) << 4;     // Ks swizzle (256-B rows)
  int vswz = ((ql >> 1) & 7) << 4;  // Vt read swizzle (128-B rows, bits 1..3)
  const float qscale = 0.08838834764831845f * 1.4426950408889634f; // /sqrt(128)*log2e

  bf16x8 qf[8];
  {
    const u16* qp = Q + (size_t)(b*NS + qa) * ND + h*NDH + hi*8;
#pragma unroll
    for (int ds = 0; ds < 8; ++ds) {
      u16x8 t = *(const u16x8*)(qp + ds*16);
      u16x8 r;
#pragma unroll
      for (int j = 0; j < 8; ++j) r[j] = f2bf(bf2f(t[j]) * qscale);
      qf[ds] = *(bf16x8*)&r;
    }
  }
  f32x16 o0 = {}, o1 = {}, o2 = {}, o3 = {};   // O dh-subtiles 0..3
  float m_run = -INFINITY, l_run = 0.f;

  const char* Kg = (const char*)(K + (size_t)b*NS*ND + h*NDH);
  const char* Vg = (const char*)(V + (size_t)b*NS*ND + h*NDH);
  const int ROWB = ND * 2;

  int p   = tid & 31;    // dh pair for V repack
  int kvg = tid >> 5;    // kv chunk 0..15 (4 kv rows each)

  auto issueKV = [&](int kv0, int buf, unsigned (&dlo)[4], unsigned (&dhi)[4]) {
    const char* vrow = Vg + (size_t)(kv0 + kvg*4) * ROWB;
#pragma unroll
    for (int j = 0; j < 4; ++j) {
      dlo[j] = *(const unsigned*)(vrow + j*ROWB + p*4);
      dhi[j] = *(const unsigned*)(vrow + j*ROWB + 128 + p*4);
    }
    char* ksb = (char*)Ks + buf*16384;
#pragma unroll
    for (int c = 0; c < 2; ++c) {
      int s = c*8192 + wv*1024 + lane*16;
      int row = s >> 8;
      int within = (s & 255) ^ ((row & 7) << 4);
      gld16(Kg + (size_t)(kv0 + row)*ROWB + within, ksb + c*8192 + wv*1024);
    }
    __builtin_amdgcn_sched_barrier(0);
  };

  auto dostep = [&](int kv0, int buf, const unsigned (&dlo)[4], const unsigned (&dhi)[4],
                    bool hasNext) {
    if (hasNext) asm volatile("s_waitcnt vmcnt(10)" ::: "memory");
    else         asm volatile("s_waitcnt vmcnt(0)"  ::: "memory");
    __builtin_amdgcn_sched_barrier(0);
    __builtin_amdgcn_s_barrier();        // BAR-A: all waves' K(t) landed
    __builtin_amdgcn_sched_barrier(0);

    char* vtb = (char*)Vt + buf*16384;
    const char* ksb = (const char*)Ks + buf*16384;

    // Vt write: rows {2p,2p+1,2p+64,2p+65} all swizzle to granule p&7
    {
      u16x4 rA, rB, rC, rD;
#pragma unroll
      for (int j = 0; j < 4; ++j) {
        rA[j] = (u16)dlo[j]; rB[j] = (u16)(dlo[j] >> 16);
        rC[j] = (u16)dhi[j]; rD[j] = (u16)(dhi[j] >> 16);
      }
      int ws = (p & 7) << 4;
      *(u16x4*)(vtb + (((2*p   )*128 + kvg*8) ^ ws)) = rA;
      *(u16x4*)(vtb + (((2*p+ 1)*128 + kvg*8) ^ ws)) = rB;
      *(u16x4*)(vtb + (((2*p+64)*128 + kvg*8) ^ ws)) = rC;
      *(u16x4*)(vtb + (((2*p+65)*128 + kvg*8) ^ ws)) = rD;
    }

    // S = K Q^T (swapped): p0 = kv 0..31, p1 = kv 32..63; lane's q = ql
    f32x16 p0 = {}, p1 = {};
    __builtin_amdgcn_s_setprio(1);
#pragma unroll
    for (int ds = 0; ds < 8; ++ds) {
      bf16x8 kf0 = *(const bf16x8*)(ksb + ((ql*256 + ds*32 + hi*16) ^ swzl));
      p0 = mfma32_bf16(kf0, qf[ds], p0);
      bf16x8 kf1 = *(const bf16x8*)(ksb + (((32+ql)*256 + ds*32 + hi*16) ^ swzl));
      p1 = mfma32_bf16(kf1, qf[ds], p1);
    }
    __builtin_amdgcn_s_setprio(0);

    // causal mask
    if (kv0 + 63 > qw) {
      int thresh = qa - kv0 - 4*hi;
#pragma unroll
      for (int r = 0; r < 16; ++r) {
        int c0 = (r & 3) + 8*(r >> 2);
        p0[r] = (c0      > thresh) ? -INFINITY : p0[r];
        p1[r] = (c0 + 32 > thresh) ? -INFINITY : p1[r];
      }
    }

    // row max (in-reg tree + one cross-pair shuffle)
    float mx[16];
#pragma unroll
    for (int r = 0; r < 16; ++r) mx[r] = fmaxf(p0[r], p1[r]);
#pragma unroll
    for (int s = 8; s > 0; s >>= 1)
#pragma unroll
      for (int r = 0; r < 8; ++r) if (r < s) mx[r] = fmaxf(mx[r], mx[r + s]);
    float pmax = fmaxf(mx[0], __shfl_xor(mx[0], 32, 64));

    // T13 defer-max
    if (!__all(pmax <= m_run + 8.f)) {
      float mn = fmaxf(m_run, pmax);
      float corr = __builtin_amdgcn_exp2f(m_run - mn);
      m_run = mn; l_run *= corr;
#pragma unroll
      for (int r = 0; r < 16; ++r) {
        float cw = __shfl(corr, (r & 3) + 8*(r >> 2) + 4*hi, 64);
        o0[r] *= cw; o1[r] *= cw; o2[r] *= cw; o3[r] *= cw;
      }
    }

    // exp2 + row sum
    float sm[16];
#pragma unroll
    for (int r = 0; r < 16; ++r) {
      p0[r] = __builtin_amdgcn_exp2f(p0[r] - m_run);
      p1[r] = __builtin_amdgcn_exp2f(p1[r] - m_run);
      sm[r] = p0[r] + p1[r];
    }
#pragma unroll
    for (int s = 8; s > 0; s >>= 1)
#pragma unroll
      for (int r = 0; r < 8; ++r) if (r < s) sm[r] += sm[r + s];
    l_run += sm[0] + __shfl_xor(sm[0], 32, 64);

    // P -> bf16 A-frags: 16 cvt_pk + 8 permlane32_swap (T12)
    bf16x8 pa0, pa1, pa2, pa3;
#define MKPA(P, B, OUT) {                              \
      unsigned a0 = cvtpk(P[(B)+0], P[(B)+1]);         \
      unsigned b0 = cvtpk(P[(B)+4], P[(B)+5]);         \
      p32swap(a0, b0);                                 \
      unsigned a1 = cvtpk(P[(B)+2], P[(B)+3]);         \
      unsigned b1 = cvtpk(P[(B)+6], P[(B)+7]);         \
      p32swap(a1, b1);                                 \
      u32x4_t w; w[0]=a0; w[1]=a1; w[2]=b0; w[3]=b1;   \
      OUT = *(bf16x8*)&w; }
    MKPA(p0, 0, pa0)
    MKPA(p0, 8, pa1)
    MKPA(p1, 0, pa2)
    MKPA(p1, 8, pa3)
#undef MKPA

    asm volatile("s_waitcnt lgkmcnt(0)" ::: "memory");  // my Vt writes done
    __builtin_amdgcn_sched_barrier(0);
    __builtin_amdgcn_s_barrier();        // BAR-B: all waves' Vt[buf] visible
    __builtin_amdgcn_sched_barrier(0);

    // O += P V
    __builtin_amdgcn_s_setprio(1);
#define PVT(OT, T) {                                                        \
      _Pragma("unroll")                                                     \
      for (int ks = 0; ks < 4; ++ks) {                                      \
        int a = ((((T)*32 + ql)*128 + ks*32 + hi*16) ^ vswz);               \
        bf16x8 vf = *(const bf16x8*)(vtb + a);                              \
        OT = mfma32_bf16(ks==0?pa0:ks==1?pa1:ks==2?pa2:pa3, vf, OT);        \
      } }
    PVT(o0, 0)
    PVT(o1, 1)
    PVT(o2, 2)
    PVT(o3, 3)
#undef PVT
    __builtin_amdgcn_s_setprio(0);
  };

  int nt = 4*qt + 4;                     // kv tiles 0 .. q0+255
  unsigned dloA[4], dhiA[4], dloB[4], dhiB[4];
  issueKV(0, 0, dloA, dhiA);
  for (int t = 0; ; t += 2) {
    bool h1 = (t+1 < nt);
    if (h1) issueKV((t+1)*64, 1, dloB, dhiB);
    dostep(t*64, 0, dloA, dhiA, h1);
    if (!h1) break;
    bool h2 = (t+2 < nt);
    if (h2) issueKV((t+2)*64, 0, dloA, dhiA);
    dostep((t+1)*64, 1, dloB, dhiB, h2);
    if (!h2) break;
  }

  // epilogue
  float inv = 1.0f / l_run;
#pragma unroll
  for (int r = 0; r < 16; ++r) {
    int crow = (r & 3) + 8*(r >> 2) + 4*hi;
    float iv = __shfl(inv, crow, 64);
    size_t base = (size_t)(b*NS + qw + crow) * ND + h*NDH + ql;
    O[base +  0] = f2bf(o0[r] * iv);
    O[base + 32] = f2bf(o1[r] * iv);
    O[base + 64] = f2bf(o2[r] * iv);
    O[base + 96] = f2bf(o3[r] * iv);
  }
}

// ---------------- launch ----------------
extern "C" void kernel_launch(void* const* d_in, const int* in_sizes, int n_in,
                              void* d_out, int out_size, void* d_ws, size_t ws_size,
                              hipStream_t stream) {
  const float* x  = (const float*)d_in[0];
  // d_in[1] = attn_mask (causal, handled analytically)
  const float* Wq = (const float*)d_in[2];
  const float* Wk = (const float*)d_in[3];
  const float* Wv = (const float*)d_in[4];
  const float* Wo = (const float*)d_in[5];

  char* ws = (char*)d_ws;
  const size_t SZ_MD = (size_t)NM * ND * 2;
  const size_t SZ_W  = (size_t)ND * ND * 2;
  u16* xb  = (u16*)(ws);
  u16* Qb  = (u16*)(ws + SZ_MD);
  u16* Kb  = (u16*)(ws + 2*SZ_MD);
  u16* Vb  = (u16*)(ws + 3*SZ_MD);
  u16* Ab  = (u16*)(ws + 4*SZ_MD);
  u16* Wqb = (u16*)(ws + 5*SZ_MD);
  u16* Wkb = (u16*)(ws + 5*SZ_MD + SZ_W);
  u16* Wvb = (u16*)(ws + 5*SZ_MD + 2*SZ_W);
  u16* Wob = (u16*)(ws + 5*SZ_MD + 3*SZ_W);
  float* cosT = (float*)(ws + 5*SZ_MD + 4*SZ_W);
  float* sinT = (float*)(ws + 5*SZ_MD + 4*SZ_W + (size_t)NS*64*4);
  size_t needed = 5*SZ_MD + 4*SZ_W + 2*(size_t)NS*64*4;
  if (ws_size < needed) return;

  {
    int n8x = (NM * ND) / 8;
    int n8w = (ND * ND) / 8;
    int tot = n8x + 4 * n8w;
    cvt5_bf16_kernel<<<(tot + 255)/256, 256, 0, stream>>>(
        x, Wq, Wk, Wv, Wo, xb, Wqb, Wkb, Wvb, Wob, n8x, n8w);
  }
  rope_tables_kernel<<<NS, 64, 0, stream>>>(cosT, sinT);

  // fused QKV projection with RoPE in the Q/K epilogue
  gemm256_kernel<u16><<<3*256, 512, 0, stream>>>(xb, Wqb, Wkb, Wvb,
                                                 Qb, Kb, Vb, cosT, sinT, ND, ND);

  flash_attn_kernel<<<dim3(NB*NH, NS/256), 512, 0, stream>>>(Qb, Kb, Vb, Ab);

  gemm256_kernel<float><<<256, 512, 0, stream>>>(Ab, Wob, nullptr, nullptr,
                                                 (float*)d_out, nullptr, nullptr,
                                                 cosT, sinT, ND, ND);
}

// Round 19
// 391.156 us; speedup vs baseline: 1.8444x; 1.0003x over previous
//
#include <hip/hip_runtime.h>
#include <cstdint>
#include <cmath>

#define NB 4
#define NS 2048
#define ND 2048
#define NH 16
#define NDH 128
#define NM (NB*NS)   // 8192

typedef unsigned short u16;
typedef __bf16 bf16x8 __attribute__((ext_vector_type(8)));
typedef u16    u16x8  __attribute__((ext_vector_type(8)));
typedef u16    u16x4  __attribute__((ext_vector_type(4)));
typedef float  f32x4  __attribute__((ext_vector_type(4)));
typedef float  f32x16 __attribute__((ext_vector_type(16)));
typedef unsigned u32x4_t __attribute__((ext_vector_type(4)));

__device__ __forceinline__ u16 f2bf(float f) {
  unsigned u = __float_as_uint(f);
  u += 0x7fffu + ((u >> 16) & 1u);   // RNE
  return (u16)(u >> 16);
}
__device__ __forceinline__ float bf2f(u16 h) {
  return __uint_as_float(((unsigned)h) << 16);
}
__device__ __forceinline__ void gld16(const void* g, void* l) {
  __builtin_amdgcn_global_load_lds((__attribute__((address_space(1))) void*)g,
                                   (__attribute__((address_space(3))) void*)l,
                                   16, 0, 0);
}
__device__ __forceinline__ f32x4 mfma_bf16(bf16x8 a, bf16x8 b, f32x4 c) {
  return __builtin_amdgcn_mfma_f32_16x16x32_bf16(a, b, c, 0, 0, 0);
}
__device__ __forceinline__ f32x16 mfma32_bf16(bf16x8 a, bf16x8 b, f32x16 c) {
  return __builtin_amdgcn_mfma_f32_32x32x16_bf16(a, b, c, 0, 0, 0);
}
__device__ __forceinline__ unsigned cvtpk(float lo, float hi) {
  unsigned r;
  asm("v_cvt_pk_bf16_f32 %0, %1, %2" : "=v"(r) : "v"(lo), "v"(hi));
  return r;
}
__device__ __forceinline__ void p32swap(unsigned &a, unsigned &b) {
  asm volatile("v_permlane32_swap_b32 %0, %1" : "+v"(a), "+v"(b));
}

// ---------------- fp32 -> bf16 convert: x + 4 weights, ONE dispatch --------
__global__ void cvt5_bf16_kernel(const float* __restrict__ ix,
                                 const float* __restrict__ i0, const float* __restrict__ i1,
                                 const float* __restrict__ i2, const float* __restrict__ i3,
                                 u16* ox, u16* o0, u16* o1, u16* o2, u16* o3,
                                 int n8x, int n8w) {
  int idx = blockIdx.x * 256 + threadIdx.x;
  const float* in;
  u16* out;
  int i;
  if (idx < n8x) { in = ix; out = ox; i = idx; }
  else {
    int r = idx - n8x;
    int w = r / n8w; i = r - w * n8w;
    if (w >= 4) return;
    in  = (w == 0) ? i0 : (w == 1) ? i1 : (w == 2) ? i2 : i3;
    out = (w == 0) ? o0 : (w == 1) ? o1 : (w == 2) ? o2 : o3;
  }
  const float4* p = (const float4*)in + (size_t)i * 2;
  float4 a = p[0], b = p[1];
  u16x8 r8;
  r8[0]=f2bf(a.x); r8[1]=f2bf(a.y); r8[2]=f2bf(a.z); r8[3]=f2bf(a.w);
  r8[4]=f2bf(b.x); r8[5]=f2bf(b.y); r8[6]=f2bf(b.z); r8[7]=f2bf(b.w);
  ((u16x8*)out)[i] = r8;
}

// ---------------- RoPE tables: cos/sin [S][64] ----------------
__global__ void rope_tables_kernel(float* __restrict__ cosT, float* __restrict__ sinT) {
  int s = blockIdx.x, d = threadIdx.x;
  double inv = pow(10000.0, -(double)d / 64.0);
  float ang = (float)((double)s * inv);
  cosT[s*64 + d] = cosf(ang);
  sinT[s*64 + d] = sinf(ang);
}

// ---------------- bf16 GEMM, 256x256 tile, 8-phase, 16x16x32 MFMA ----------
// R18 form: RoPE fused into the Q/K epilogue via B-fragment column remap
// (frag nf covers col (wc>>1)*128+(wc&1)*32+(nf&1)*16+(nf>>1)*64+li; nf and
// nf+2 are RoPE partners d,d+64 within one head).  Schedule = R13 (best):
// barriers at even phases, vmcnt(4) at phases 4/8; conflict-free swizzle.
#define BARX do { __builtin_amdgcn_s_barrier(); __builtin_amdgcn_sched_barrier(0); } while (0)
#define VM4  do { asm volatile("s_waitcnt vmcnt(4)" ::: "memory"); \
                  __builtin_amdgcn_sched_barrier(0); } while (0)
#define GP(BUF, KS, MH, LOADB, WAITV, DOBAR, STAGE) do {                          \
  bf16x8 af[4];                                                                   \
  _Pragma("unroll")                                                               \
  for (int mf = 0; mf < 4; ++mf)                                                  \
    af[mf] = *(const bf16x8*)(Asb + (BUF)*32768 + (KS)*16384 + arow + ((MH)*4+mf)*1024); \
  if (LOADB) {                                                                    \
    _Pragma("unroll")                                                             \
    for (int nf = 0; nf < 4; ++nf)                                                \
      bfr[nf] = *(const bf16x8*)(Bsb + (BUF)*32768 + (KS)*16384 + brow            \
                                 + (nf & 1)*1024 + (nf >> 1)*4096);               \
  }                                                                               \
  STAGE;                                                                          \
  __builtin_amdgcn_s_setprio(1);                                                  \
  _Pragma("unroll")                                                               \
  for (int mf = 0; mf < 4; ++mf)                                                  \
    _Pragma("unroll")                                                             \
    for (int nf = 0; nf < 4; ++nf)                                                \
      acc[(MH)*4+mf][nf] = mfma_bf16(af[mf], bfr[nf], acc[(MH)*4+mf][nf]);        \
  __builtin_amdgcn_s_setprio(0);                                                  \
  if (WAITV) VM4;                                                                 \
  if (DOBAR) BARX;                                                                \
} while (0)

template <typename OutT>
__global__ __launch_bounds__(512, 2) void gemm256_kernel(
    const u16* __restrict__ A,
    const u16* __restrict__ B0, const u16* __restrict__ B1, const u16* __restrict__ B2,
    OutT* __restrict__ C0, OutT* __restrict__ C1, OutT* __restrict__ C2,
    const float* __restrict__ cosT, const float* __restrict__ sinT,
    int Nd, int Kd) {
  __shared__ __align__(16) char Asb[65536];
  __shared__ __align__(16) char Bsb[65536];
  int tid = threadIdx.x;
  int wave = tid >> 6, lane = tid & 63;
  int li = lane & 15, lg = lane >> 4;
  int wr = wave >> 2, wc = wave & 3;           // 2 x 4 wave grid
  int w  = (int)blockIdx.x >> 8;               // matrix select (fused QKV)
  int tb = (int)blockIdx.x & 255;
  const u16* Bw = (w == 0) ? B0 : (w == 1) ? B1 : B2;
  OutT*      C  = (w == 0) ? C0 : (w == 1) ? C1 : C2;
  int NTn = Nd >> 8;
  int swz = (tb & 7) * 32 + (tb >> 3);         // XCD swizzle over 256 tiles
  int m0 = (swz / NTn) << 8, n0 = (swz % NTn) << 8;

  int rswz = (lg * 16) ^ (((li >> 1) & 3) << 4);
  int arow = (wr * 128 + li) * 64 + rswz;
  int bcol0 = (wc >> 1)*128 + (wc & 1)*32;     // wave's within-tile col base
  int brow = (bcol0 + li) * 64 + rswz;

  int srow = wave * 16 + (lane >> 2);
  int scswz = ((lane & 3) * 16) ^ (((srow >> 1) & 3) << 4);
  size_t rowB = (size_t)Kd * 2;
  const char* Asrc = (const char*)A  + (size_t)(m0 + srow) * rowB + scswz;
  const char* Bsrc = (const char*)Bw + (size_t)(n0 + srow) * rowB + scswz;
  char* Adst = Asb + wave * 1024;
  char* Bdst = Bsb + wave * 1024;
  size_t half2 = rowB << 7;

  auto stageA = [&](int buf, int ks, int tile) {
    const char* s = Asrc + (size_t)tile * 128 + ks * 64;
    char* d = Adst + buf * 32768 + ks * 16384;
    gld16(s, d);
    gld16(s + half2, d + 8192);
  };
  auto stageB = [&](int buf, int ks, int tile) {
    const char* s = Bsrc + (size_t)tile * 128 + ks * 64;
    char* d = Bdst + buf * 32768 + ks * 16384;
    gld16(s, d);
    gld16(s + half2, d + 8192);
  };

  f32x4 acc[8][4] = {};
  bf16x8 bfr[4];

  int NKT = Kd >> 6;
  int NIT = NKT >> 1;

  stageA(0, 0, 0); stageA(0, 1, 0); stageB(0, 0, 0); stageB(0, 1, 0);
  stageA(1, 0, 1); stageB(1, 0, 1);
  asm volatile("s_waitcnt vmcnt(4)" ::: "memory");
  __builtin_amdgcn_sched_barrier(0);
  BARX;

  for (int j = 0; j < NIT; ++j) {
    int t1  = 2*j + 1;
    int tn0 = (2*j + 2) & (NKT - 1);
    int tn1 = (2*j + 3) & (NKT - 1);
    GP(0, 0, 0, true,  false, false, { stageA(1, 1, t1);  });
    GP(0, 0, 1, false, false, true,  { stageB(1, 1, t1);  });
    GP(0, 1, 1, true,  false, false, { stageA(0, 0, tn0); });
    GP(0, 1, 0, false, true,  true,  { stageB(0, 0, tn0); });
    GP(1, 0, 0, true,  false, false, { stageA(0, 1, tn0); });
    GP(1, 0, 1, false, false, true,  { stageB(0, 1, tn0); });
    GP(1, 1, 1, true,  false, false, { stageA(1, 0, tn1); });
    GP(1, 1, 0, false, true,  true,  { stageB(1, 0, tn1); });
  }
  asm volatile("s_waitcnt vmcnt(0)" ::: "memory");

  // epilogue: C row = rbase + am*16 + r; col = n0 + bcol0 + (nf&1)*16
  //           + (nf>>1)*64 + li  [C/D map m89/m91]
  int rbase = m0 + wr*128 + lg*4;
  int cbase = n0 + bcol0 + li;
  if constexpr (sizeof(OutT) == 2) {
    if (w < 2) {
      // RoPE on fp32 acc: pair (nf2, nf2+2) = (d, d+64) within one head
      int dbase = (wc & 1)*32 + li;          // within-head d, [0,64)
#pragma unroll
      for (int am = 0; am < 8; ++am)
#pragma unroll
        for (int r = 0; r < 4; ++r) {
          int grow = rbase + am*16 + r;
          int s = grow & (NS - 1);
          const float* cp = cosT + s*64 + dbase;
          const float* sp = sinT + s*64 + dbase;
#pragma unroll
          for (int nf2 = 0; nf2 < 2; ++nf2) {
            float c  = cp[nf2*16];
            float sn = sp[nf2*16];
            float v0 = acc[am][nf2][r];
            float v1 = acc[am][nf2+2][r];
            size_t off = (size_t)grow * Nd + (cbase + nf2*16);
            C[off]      = f2bf(v0*c - v1*sn);
            C[off + 64] = f2bf(v1*c + v0*sn);
          }
        }
    } else {
#pragma unroll
      for (int am = 0; am < 8; ++am)
#pragma unroll
        for (int nf = 0; nf < 4; ++nf)
#pragma unroll
          for (int r = 0; r < 4; ++r) {
            size_t off = (size_t)(rbase + am*16 + r) * Nd
                         + (cbase + (nf & 1)*16 + (nf >> 1)*64);
            C[off] = f2bf(acc[am][nf][r]);
          }
    }
  } else {
#pragma unroll
    for (int am = 0; am < 8; ++am)
#pragma unroll
      for (int nf = 0; nf < 4; ++nf)
#pragma unroll
        for (int r = 0; r < 4; ++r) {
          size_t off = (size_t)(rbase + am*16 + r) * Nd
                       + (cbase + (nf & 1)*16 + (nf >> 1)*64);
          C[off] = acc[am][nf][r];
        }
  }
}

// ---------------- causal flash attention, 32x32 swapped-QK^T ----------------
// R19: single-buffer Vt (48 KB LDS total -> 3 blocks/CU, 24 waves).
// WAR proof: Vt(t+1) writes occur after BAR-A(t+1); every wave reaches
// BAR-A(t+1) only after its PV(t) MFMAs issued, whose ds_reads completed
// (compiler lgkm waits) — so all PV(t) reads of Vt finish before any wave
// can overwrite it.  Ks stays double-buffered; vmcnt(10) ledger unchanged
// (V loads land in registers, not LDS).
__global__ __launch_bounds__(512, 2) void flash_attn_kernel(
    const u16* __restrict__ Q, const u16* __restrict__ K, const u16* __restrict__ V,
    u16* __restrict__ O) {
  __shared__ __align__(16) u16 Ks[2*64*128];  // 32 KB swizzled [kv][dh], dbuf
  __shared__ __align__(16) u16 Vt[128*64];    // 16 KB swizzled [dh][kv], single
  int tid = threadIdx.x, wv = tid >> 6, lane = tid & 63;
  int ql = lane & 31, hi = lane >> 5;
  int b = blockIdx.x >> 4, h = blockIdx.x & 15;
  int qt = (int)gridDim.y - 1 - (int)blockIdx.y;   // heavy first
  int q0 = qt << 8;
  int qw = q0 + wv*32;          // wave q base
  int qa = qw + ql;             // this lane's q row
  int swzl = (ql & 7) << 4;     // Ks swizzle (256-B rows)
  int vswz = ((ql >> 1) & 7) << 4;  // Vt read swizzle (128-B rows, bits 1..3)
  const float qscale = 0.08838834764831845f * 1.4426950408889634f; // /sqrt(128)*log2e

  bf16x8 qf[8];
  {
    const u16* qp = Q + (size_t)(b*NS + qa) * ND + h*NDH + hi*8;
#pragma unroll
    for (int ds = 0; ds < 8; ++ds) {
      u16x8 t = *(const u16x8*)(qp + ds*16);
      u16x8 r;
#pragma unroll
      for (int j = 0; j < 8; ++j) r[j] = f2bf(bf2f(t[j]) * qscale);
      qf[ds] = *(bf16x8*)&r;
    }
  }
  f32x16 o0 = {}, o1 = {}, o2 = {}, o3 = {};   // O dh-subtiles 0..3
  float m_run = -INFINITY, l_run = 0.f;

  const char* Kg = (const char*)(K + (size_t)b*NS*ND + h*NDH);
  const char* Vg = (const char*)(V + (size_t)b*NS*ND + h*NDH);
  const int ROWB = ND * 2;

  int p   = tid & 31;    // dh pair for V repack
  int kvg = tid >> 5;    // kv chunk 0..15 (4 kv rows each)

  auto issueKV = [&](int kv0, int buf, unsigned (&dlo)[4], unsigned (&dhi)[4]) {
    const char* vrow = Vg + (size_t)(kv0 + kvg*4) * ROWB;
#pragma unroll
    for (int j = 0; j < 4; ++j) {
      dlo[j] = *(const unsigned*)(vrow + j*ROWB + p*4);
      dhi[j] = *(const unsigned*)(vrow + j*ROWB + 128 + p*4);
    }
    char* ksb = (char*)Ks + buf*16384;
#pragma unroll
    for (int c = 0; c < 2; ++c) {
      int s = c*8192 + wv*1024 + lane*16;
      int row = s >> 8;
      int within = (s & 255) ^ ((row & 7) << 4);
      gld16(Kg + (size_t)(kv0 + row)*ROWB + within, ksb + c*8192 + wv*1024);
    }
    __builtin_amdgcn_sched_barrier(0);
  };

  auto dostep = [&](int kv0, int buf, const unsigned (&dlo)[4], const unsigned (&dhi)[4],
                    bool hasNext) {
    if (hasNext) asm volatile("s_waitcnt vmcnt(10)" ::: "memory");
    else         asm volatile("s_waitcnt vmcnt(0)"  ::: "memory");
    __builtin_amdgcn_sched_barrier(0);
    __builtin_amdgcn_s_barrier();        // BAR-A: all waves' K(t) landed,
                                         //        all PV(t-1) reads complete
    __builtin_amdgcn_sched_barrier(0);

    char* vtb = (char*)Vt;               // single buffer
    const char* ksb = (const char*)Ks + buf*16384;

    // Vt write: rows {2p,2p+1,2p+64,2p+65} all swizzle to granule p&7
    {
      u16x4 rA, rB, rC, rD;
#pragma unroll
      for (int j = 0; j < 4; ++j) {
        rA[j] = (u16)dlo[j]; rB[j] = (u16)(dlo[j] >> 16);
        rC[j] = (u16)dhi[j]; rD[j] = (u16)(dhi[j] >> 16);
      }
      int ws = (p & 7) << 4;
      *(u16x4*)(vtb + (((2*p   )*128 + kvg*8) ^ ws)) = rA;
      *(u16x4*)(vtb + (((2*p+ 1)*128 + kvg*8) ^ ws)) = rB;
      *(u16x4*)(vtb + (((2*p+64)*128 + kvg*8) ^ ws)) = rC;
      *(u16x4*)(vtb + (((2*p+65)*128 + kvg*8) ^ ws)) = rD;
    }

    // S = K Q^T (swapped): p0 = kv 0..31, p1 = kv 32..63; lane's q = ql
    f32x16 p0 = {}, p1 = {};
    __builtin_amdgcn_s_setprio(1);
#pragma unroll
    for (int ds = 0; ds < 8; ++ds) {
      bf16x8 kf0 = *(const bf16x8*)(ksb + ((ql*256 + ds*32 + hi*16) ^ swzl));
      p0 = mfma32_bf16(kf0, qf[ds], p0);
      bf16x8 kf1 = *(const bf16x8*)(ksb + (((32+ql)*256 + ds*32 + hi*16) ^ swzl));
      p1 = mfma32_bf16(kf1, qf[ds], p1);
    }
    __builtin_amdgcn_s_setprio(0);

    // causal mask
    if (kv0 + 63 > qw) {
      int thresh = qa - kv0 - 4*hi;
#pragma unroll
      for (int r = 0; r < 16; ++r) {
        int c0 = (r & 3) + 8*(r >> 2);
        p0[r] = (c0      > thresh) ? -INFINITY : p0[r];
        p1[r] = (c0 + 32 > thresh) ? -INFINITY : p1[r];
      }
    }

    // row max (in-reg tree + one cross-pair shuffle)
    float mx[16];
#pragma unroll
    for (int r = 0; r < 16; ++r) mx[r] = fmaxf(p0[r], p1[r]);
#pragma unroll
    for (int s = 8; s > 0; s >>= 1)
#pragma unroll
      for (int r = 0; r < 8; ++r) if (r < s) mx[r] = fmaxf(mx[r], mx[r + s]);
    float pmax = fmaxf(mx[0], __shfl_xor(mx[0], 32, 64));

    // T13 defer-max
    if (!__all(pmax <= m_run + 8.f)) {
      float mn = fmaxf(m_run, pmax);
      float corr = __builtin_amdgcn_exp2f(m_run - mn);
      m_run = mn; l_run *= corr;
#pragma unroll
      for (int r = 0; r < 16; ++r) {
        float cw = __shfl(corr, (r & 3) + 8*(r >> 2) + 4*hi, 64);
        o0[r] *= cw; o1[r] *= cw; o2[r] *= cw; o3[r] *= cw;
      }
    }

    // exp2 + row sum
    float sm[16];
#pragma unroll
    for (int r = 0; r < 16; ++r) {
      p0[r] = __builtin_amdgcn_exp2f(p0[r] - m_run);
      p1[r] = __builtin_amdgcn_exp2f(p1[r] - m_run);
      sm[r] = p0[r] + p1[r];
    }
#pragma unroll
    for (int s = 8; s > 0; s >>= 1)
#pragma unroll
      for (int r = 0; r < 8; ++r) if (r < s) sm[r] += sm[r + s];
    l_run += sm[0] + __shfl_xor(sm[0], 32, 64);

    // P -> bf16 A-frags: 16 cvt_pk + 8 permlane32_swap (T12)
    bf16x8 pa0, pa1, pa2, pa3;
#define MKPA(P, B, OUT) {                              \
      unsigned a0 = cvtpk(P[(B)+0], P[(B)+1]);         \
      unsigned b0 = cvtpk(P[(B)+4], P[(B)+5]);         \
      p32swap(a0, b0);                                 \
      unsigned a1 = cvtpk(P[(B)+2], P[(B)+3]);         \
      unsigned b1 = cvtpk(P[(B)+6], P[(B)+7]);         \
      p32swap(a1, b1);                                 \
      u32x4_t w; w[0]=a0; w[1]=a1; w[2]=b0; w[3]=b1;   \
      OUT = *(bf16x8*)&w; }
    MKPA(p0, 0, pa0)
    MKPA(p0, 8, pa1)
    MKPA(p1, 0, pa2)
    MKPA(p1, 8, pa3)
#undef MKPA

    asm volatile("s_waitcnt lgkmcnt(0)" ::: "memory");  // my Vt writes done
    __builtin_amdgcn_sched_barrier(0);
    __builtin_amdgcn_s_barrier();        // BAR-B: all waves' Vt visible
    __builtin_amdgcn_sched_barrier(0);

    // O += P V
    __builtin_amdgcn_s_setprio(1);
#define PVT(OT, T) {                                                        \
      _Pragma("unroll")                                                     \
      for (int ks = 0; ks < 4; ++ks) {                                      \
        int a = ((((T)*32 + ql)*128 + ks*32 + hi*16) ^ vswz);               \
        bf16x8 vf = *(const bf16x8*)(vtb + a);                              \
        OT = mfma32_bf16(ks==0?pa0:ks==1?pa1:ks==2?pa2:pa3, vf, OT);        \
      } }
    PVT(o0, 0)
    PVT(o1, 1)
    PVT(o2, 2)
    PVT(o3, 3)
#undef PVT
    __builtin_amdgcn_s_setprio(0);
  };

  int nt = 4*qt + 4;                     // kv tiles 0 .. q0+255
  unsigned dloA[4], dhiA[4], dloB[4], dhiB[4];
  issueKV(0, 0, dloA, dhiA);
  for (int t = 0; ; t += 2) {
    bool h1 = (t+1 < nt);
    if (h1) issueKV((t+1)*64, 1, dloB, dhiB);
    dostep(t*64, 0, dloA, dhiA, h1);
    if (!h1) break;
    bool h2 = (t+2 < nt);
    if (h2) issueKV((t+2)*64, 0, dloA, dhiA);
    dostep((t+1)*64, 1, dloB, dhiB, h2);
    if (!h2) break;
  }

  // epilogue
  float inv = 1.0f / l_run;
#pragma unroll
  for (int r = 0; r < 16; ++r) {
    int crow = (r & 3) + 8*(r >> 2) + 4*hi;
    float iv = __shfl(inv, crow, 64);
    size_t base = (size_t)(b*NS + qw + crow) * ND + h*NDH + ql;
    O[base +  0] = f2bf(o0[r] * iv);
    O[base + 32] = f2bf(o1[r] * iv);
    O[base + 64] = f2bf(o2[r] * iv);
    O[base + 96] = f2bf(o3[r] * iv);
  }
}

// ---------------- launch ----------------
extern "C" void kernel_launch(void* const* d_in, const int* in_sizes, int n_in,
                              void* d_out, int out_size, void* d_ws, size_t ws_size,
                              hipStream_t stream) {
  const float* x  = (const float*)d_in[0];
  // d_in[1] = attn_mask (causal, handled analytically)
  const float* Wq = (const float*)d_in[2];
  const float* Wk = (const float*)d_in[3];
  const float* Wv = (const float*)d_in[4];
  const float* Wo = (const float*)d_in[5];

  char* ws = (char*)d_ws;
  const size_t SZ_MD = (size_t)NM * ND * 2;
  const size_t SZ_W  = (size_t)ND * ND * 2;
  u16* xb  = (u16*)(ws);
  u16* Qb  = (u16*)(ws + SZ_MD);
  u16* Kb  = (u16*)(ws + 2*SZ_MD);
  u16* Vb  = (u16*)(ws + 3*SZ_MD);
  u16* Ab  = (u16*)(ws + 4*SZ_MD);
  u16* Wqb = (u16*)(ws + 5*SZ_MD);
  u16* Wkb = (u16*)(ws + 5*SZ_MD + SZ_W);
  u16* Wvb = (u16*)(ws + 5*SZ_MD + 2*SZ_W);
  u16* Wob = (u16*)(ws + 5*SZ_MD + 3*SZ_W);
  float* cosT = (float*)(ws + 5*SZ_MD + 4*SZ_W);
  float* sinT = (float*)(ws + 5*SZ_MD + 4*SZ_W + (size_t)NS*64*4);
  size_t needed = 5*SZ_MD + 4*SZ_W + 2*(size_t)NS*64*4;
  if (ws_size < needed) return;

  {
    int n8x = (NM * ND) / 8;
    int n8w = (ND * ND) / 8;
    int tot = n8x + 4 * n8w;
    cvt5_bf16_kernel<<<(tot + 255)/256, 256, 0, stream>>>(
        x, Wq, Wk, Wv, Wo, xb, Wqb, Wkb, Wvb, Wob, n8x, n8w);
  }
  rope_tables_kernel<<<NS, 64, 0, stream>>>(cosT, sinT);

  // fused QKV projection with RoPE in the Q/K epilogue
  gemm256_kernel<u16><<<3*256, 512, 0, stream>>>(xb, Wqb, Wkb, Wvb,
                                                 Qb, Kb, Vb, cosT, sinT, ND, ND);

  flash_attn_kernel<<<dim3(NB*NH, NS/256), 512, 0, stream>>>(Qb, Kb, Vb, Ab);

  gemm256_kernel<float><<<256, 512, 0, stream>>>(Ab, Wob, nullptr, nullptr,
                                                 (float*)d_out, nullptr, nullptr,
                                                 cosT, sinT, ND, ND);
}